// Round 3
// baseline (8960.754 us; speedup 1.0000x reference)
//
#include <hip/hip_runtime.h>
#include <math.h>

namespace {
constexpr int NLEV = 16;
constexpr unsigned TSZ = 1u << 19;
constexpr int HID = 64;

struct LevelParams {
    float scale[NLEV];
    unsigned res[NLEV];
    unsigned hashed_mask;
};
} // namespace

__global__ __launch_bounds__(256) void ngp_fused_kernel(
    const float* __restrict__ pos,
    const float* __restrict__ dirs,
    const float* __restrict__ aabb,
    const float* __restrict__ table,
    const float* __restrict__ wb1,
    const float* __restrict__ wb2,
    const float* __restrict__ wh1,
    const float* __restrict__ wh2,
    const float* __restrict__ wh3,
    float* __restrict__ out,
    int n, LevelParams lp)
{
    int i = blockIdx.x * blockDim.x + threadIdx.x;
    if (i >= n) return;

    float px = pos[3*i+0], py = pos[3*i+1], pz = pos[3*i+2];
    float mn0 = aabb[0], mn1 = aabb[1], mn2 = aabb[2];
    float mx0 = aabb[3], mx1 = aabb[4], mx2 = aabb[5];
    float x = (px - mn0) / (mx0 - mn0);
    float y = (py - mn1) / (mx1 - mn1);
    float z = (pz - mn2) / (mx2 - mn2);

    // ---- hash-grid encode: 16 levels x 2 features ----
    float enc[2*NLEV];
    #pragma unroll
    for (int l = 0; l < NLEV; ++l) {
        float s = lp.scale[l];
        unsigned res = lp.res[l];
        bool hashed = (lp.hashed_mask >> l) & 1u;
        float xs = fmaf(x, s, 0.5f);
        float ys = fmaf(y, s, 0.5f);
        float zs = fmaf(z, s, 0.5f);
        float fx = floorf(xs), fy = floorf(ys), fz = floorf(zs);
        float wx = xs - fx, wy = ys - fy, wz = zs - fz;
        unsigned ux = (unsigned)fx, uy = (unsigned)fy, uz = (unsigned)fz;
        const float2* tl = (const float2*)table + (size_t)l * TSZ;
        float a0 = 0.f, a1 = 0.f;
        #pragma unroll
        for (int c = 0; c < 8; ++c) {
            unsigned cx = ux + (c & 1);
            unsigned cy = uy + ((c >> 1) & 1);
            unsigned cz = uz + ((c >> 2) & 1);
            unsigned idx;
            if (hashed)
                idx = (cx ^ (cy * 2654435761u) ^ (cz * 805459861u)) & (TSZ - 1u);
            else
                idx = cx + cy * res + cz * res * res;
            float cw = ((c & 1) ? wx : 1.f - wx)
                     * (((c >> 1) & 1) ? wy : 1.f - wy)
                     * (((c >> 2) & 1) ? wz : 1.f - wz);
            float2 f = tl[idx];
            a0 = fmaf(f.x, cw, a0);
            a1 = fmaf(f.y, cw, a1);
        }
        enc[2*l]   = a0;
        enc[2*l+1] = a1;
    }

    // ---- base MLP: [32] -> relu[64] -> [16] ----
    float h[HID];
    #pragma unroll
    for (int j = 0; j < HID; ++j) h[j] = 0.f;
    #pragma unroll
    for (int k = 0; k < 2*NLEV; ++k) {
        float e = enc[k];
        #pragma unroll
        for (int j = 0; j < HID; ++j)
            h[j] = fmaf(e, wb1[k*HID+j], h[j]);
    }
    #pragma unroll
    for (int j = 0; j < HID; ++j) h[j] = fmaxf(h[j], 0.f);

    float bo[16];
    #pragma unroll
    for (int j = 0; j < 16; ++j) bo[j] = 0.f;
    #pragma unroll
    for (int k = 0; k < HID; ++k) {
        float e = h[k];
        #pragma unroll
        for (int j = 0; j < 16; ++j)
            bo[j] = fmaf(e, wb2[k*16+j], bo[j]);
    }
    float density = expf(bo[0] - 1.0f);

    // ---- SH degree-4 encode of direction ----
    float t0 = (dirs[3*i+0] + 1.f) * 0.5f;
    float t1 = (dirs[3*i+1] + 1.f) * 0.5f;
    float t2 = (dirs[3*i+2] + 1.f) * 0.5f;
    float dx = t0*2.f - 1.f, dy = t1*2.f - 1.f, dz = t2*2.f - 1.f;
    float x2 = dx*dx, y2 = dy*dy, z2 = dz*dz;
    float xy = dx*dy, xz = dx*dz, yz = dy*dz;
    float hh[31];
    hh[0]  = 0.28209479177387814f;
    hh[1]  = -0.48860251190291987f * dy;
    hh[2]  = 0.48860251190291987f * dz;
    hh[3]  = -0.48860251190291987f * dx;
    hh[4]  = 1.0925484305920792f * xy;
    hh[5]  = -1.0925484305920792f * yz;
    hh[6]  = 0.94617469575756f * z2 - 0.31539156525252f;
    hh[7]  = -1.0925484305920792f * xz;
    hh[8]  = 0.5462742152960396f * x2 - 0.5462742152960396f * y2;
    hh[9]  = 0.5900435899266435f * dy * (-3.f*x2 + y2);
    hh[10] = 2.890611442640554f * xy * dz;
    hh[11] = 0.4570457994644657f * dy * (1.f - 5.f*z2);
    hh[12] = 0.3731763325901154f * dz * (5.f*z2 - 3.f);
    hh[13] = 0.4570457994644657f * dx * (1.f - 5.f*z2);
    hh[14] = 1.445305721320277f * dz * (x2 - y2);
    hh[15] = 0.5900435899266435f * dx * (x2 - 3.f*y2);
    #pragma unroll
    for (int j = 0; j < 15; ++j) hh[16+j] = bo[1+j];

    // ---- head MLP: [31] -> relu[64] -> relu[64] -> sigmoid[3] ----
    float h1[HID];
    #pragma unroll
    for (int j = 0; j < HID; ++j) h1[j] = 0.f;
    #pragma unroll
    for (int k = 0; k < 31; ++k) {
        float e = hh[k];
        #pragma unroll
        for (int j = 0; j < HID; ++j)
            h1[j] = fmaf(e, wh1[k*HID+j], h1[j]);
    }
    #pragma unroll
    for (int j = 0; j < HID; ++j) h1[j] = fmaxf(h1[j], 0.f);

    float h2[HID];
    #pragma unroll
    for (int j = 0; j < HID; ++j) h2[j] = 0.f;
    #pragma unroll
    for (int k = 0; k < HID; ++k) {
        float e = h1[k];
        #pragma unroll
        for (int j = 0; j < HID; ++j)
            h2[j] = fmaf(e, wh2[k*HID+j], h2[j]);
    }
    #pragma unroll
    for (int j = 0; j < HID; ++j) h2[j] = fmaxf(h2[j], 0.f);

    float r0 = 0.f, r1 = 0.f, r2 = 0.f;
    #pragma unroll
    for (int k = 0; k < HID; ++k) {
        float e = h2[k];
        r0 = fmaf(e, wh3[k*3+0], r0);
        r1 = fmaf(e, wh3[k*3+1], r1);
        r2 = fmaf(e, wh3[k*3+2], r2);
    }
    r0 = 1.f / (1.f + expf(-r0));
    r1 = 1.f / (1.f + expf(-r1));
    r2 = 1.f / (1.f + expf(-r2));

    out[3*i+0] = r0;
    out[3*i+1] = r1;
    out[3*i+2] = r2;
    out[(size_t)3*n + i] = density;
}

extern "C" void kernel_launch(void* const* d_in, const int* in_sizes, int n_in,
                              void* d_out, int out_size, void* d_ws, size_t ws_size,
                              hipStream_t stream) {
    const float* pos   = (const float*)d_in[0];
    const float* dirs  = (const float*)d_in[1];
    const float* aabb  = (const float*)d_in[2];
    const float* table = (const float*)d_in[3];
    const float* wb1   = (const float*)d_in[4];
    const float* wb2   = (const float*)d_in[5];
    const float* wh1   = (const float*)d_in[6];
    const float* wh2   = (const float*)d_in[7];
    const float* wh3   = (const float*)d_in[8];
    float* out = (float*)d_out;
    int n = in_sizes[0] / 3;

    LevelParams lp;
    lp.hashed_mask = 0;
    double pls = exp((log(4096.0) - log(16.0)) / 15.0);
    for (int l = 0; l < NLEV; ++l) {
        double scale = 16.0 * pow(pls, (double)l) - 1.0;
        unsigned res = (unsigned)ceil(scale) + 1u;
        lp.scale[l] = (float)scale;
        lp.res[l] = res;
        if ((unsigned long long)res*(unsigned long long)res*(unsigned long long)res
            > (unsigned long long)TSZ)
            lp.hashed_mask |= (1u << l);
    }

    int block = 256;
    int grid = (n + block - 1) / block;
    ngp_fused_kernel<<<grid, block, 0, stream>>>(pos, dirs, aabb, table,
        wb1, wb2, wh1, wh2, wh3, out, n, lp);
}

// Round 4
// 2154.880 us; speedup vs baseline: 4.1584x; 4.1584x over previous
//
#include <hip/hip_runtime.h>
#include <math.h>

namespace {
constexpr int NLEV = 16;
constexpr unsigned TSZ = 1u << 19;
constexpr int HID = 64;

struct LevelParams {
    float scale[NLEV];
    unsigned res[NLEV];
    unsigned hashed_mask;
};
} // namespace

// ---------------------------------------------------------------
// Pass 1: hash-grid encode. One thread per (point, level).
// Block = 256 threads = 16 points x 16 levels. Low VGPR -> max
// occupancy -> many outstanding gathers (latency hiding).
// enc layout: feature-major [32][N].
// ---------------------------------------------------------------
__global__ __launch_bounds__(256) void ngp_encode_kernel(
    const float* __restrict__ pos,
    const float* __restrict__ aabb,
    const float* __restrict__ table,
    float* __restrict__ enc,
    int n)
{
    int t = blockIdx.x * 256 + threadIdx.x;
    int p = t >> 4;
    int l = t & 15;
    if (p >= n) return;

    float mn0 = aabb[0], mn1 = aabb[1], mn2 = aabb[2];
    float mx0 = aabb[3], mx1 = aabb[4], mx2 = aabb[5];
    float x = (pos[3*p+0] - mn0) / (mx0 - mn0);
    float y = (pos[3*p+1] - mn1) / (mx1 - mn1);
    float z = (pos[3*p+2] - mn2) / (mx2 - mn2);

    // scale = 16 * (2^(8/15))^l - 1 = 2^(4 + 8l/15) - 1
    float s = exp2f(fmaf((float)l, 8.0f / 15.0f, 4.0f)) - 1.0f;
    unsigned res = (unsigned)ceilf(s) + 1u;
    bool hashed = (unsigned long long)res * res * res > (unsigned long long)TSZ;

    float xs = fmaf(x, s, 0.5f);
    float ys = fmaf(y, s, 0.5f);
    float zs = fmaf(z, s, 0.5f);
    float fx = floorf(xs), fy = floorf(ys), fz = floorf(zs);
    float wx = xs - fx, wy = ys - fy, wz = zs - fz;
    unsigned ux = (unsigned)fx, uy = (unsigned)fy, uz = (unsigned)fz;

    const float2* tl = (const float2*)table + (size_t)l * TSZ;
    float a0 = 0.f, a1 = 0.f;
    #pragma unroll
    for (int c = 0; c < 8; ++c) {
        unsigned cx = ux + (c & 1);
        unsigned cy = uy + ((c >> 1) & 1);
        unsigned cz = uz + ((c >> 2) & 1);
        unsigned idx;
        if (hashed)
            idx = (cx ^ (cy * 2654435761u) ^ (cz * 805459861u)) & (TSZ - 1u);
        else
            idx = cx + cy * res + cz * res * res;
        float cw = ((c & 1) ? wx : 1.f - wx)
                 * (((c >> 1) & 1) ? wy : 1.f - wy)
                 * (((c >> 2) & 1) ? wz : 1.f - wz);
        float2 f = tl[idx];
        a0 = fmaf(f.x, cw, a0);
        a1 = fmaf(f.y, cw, a1);
    }
    enc[(size_t)(2*l)     * n + p] = a0;
    enc[(size_t)(2*l + 1) * n + p] = a1;
}

// ---------------------------------------------------------------
// Pass 2: MLPs. One thread per point, f32 scalar (proven path).
// ---------------------------------------------------------------
__global__ __launch_bounds__(256) void ngp_mlp_kernel(
    const float* __restrict__ enc,
    const float* __restrict__ dirs,
    const float* __restrict__ wb1,
    const float* __restrict__ wb2,
    const float* __restrict__ wh1,
    const float* __restrict__ wh2,
    const float* __restrict__ wh3,
    float* __restrict__ out,
    int n)
{
    int i = blockIdx.x * blockDim.x + threadIdx.x;
    if (i >= n) return;

    float encv[2*NLEV];
    #pragma unroll
    for (int k = 0; k < 2*NLEV; ++k)
        encv[k] = enc[(size_t)k * n + i];

    // ---- base MLP: [32] -> relu[64] -> [16] ----
    float h[HID];
    #pragma unroll
    for (int j = 0; j < HID; ++j) h[j] = 0.f;
    #pragma unroll
    for (int k = 0; k < 2*NLEV; ++k) {
        float e = encv[k];
        #pragma unroll
        for (int j = 0; j < HID; ++j)
            h[j] = fmaf(e, wb1[k*HID+j], h[j]);
    }
    #pragma unroll
    for (int j = 0; j < HID; ++j) h[j] = fmaxf(h[j], 0.f);

    float bo[16];
    #pragma unroll
    for (int j = 0; j < 16; ++j) bo[j] = 0.f;
    #pragma unroll
    for (int k = 0; k < HID; ++k) {
        float e = h[k];
        #pragma unroll
        for (int j = 0; j < 16; ++j)
            bo[j] = fmaf(e, wb2[k*16+j], bo[j]);
    }
    float density = expf(bo[0] - 1.0f);

    // ---- SH degree-4 encode ----
    float t0 = (dirs[3*i+0] + 1.f) * 0.5f;
    float t1 = (dirs[3*i+1] + 1.f) * 0.5f;
    float t2 = (dirs[3*i+2] + 1.f) * 0.5f;
    float dx = t0*2.f - 1.f, dy = t1*2.f - 1.f, dz = t2*2.f - 1.f;
    float x2 = dx*dx, y2 = dy*dy, z2 = dz*dz;
    float xy = dx*dy, xz = dx*dz, yz = dy*dz;
    float hh[31];
    hh[0]  = 0.28209479177387814f;
    hh[1]  = -0.48860251190291987f * dy;
    hh[2]  = 0.48860251190291987f * dz;
    hh[3]  = -0.48860251190291987f * dx;
    hh[4]  = 1.0925484305920792f * xy;
    hh[5]  = -1.0925484305920792f * yz;
    hh[6]  = 0.94617469575756f * z2 - 0.31539156525252f;
    hh[7]  = -1.0925484305920792f * xz;
    hh[8]  = 0.5462742152960396f * x2 - 0.5462742152960396f * y2;
    hh[9]  = 0.5900435899266435f * dy * (-3.f*x2 + y2);
    hh[10] = 2.890611442640554f * xy * dz;
    hh[11] = 0.4570457994644657f * dy * (1.f - 5.f*z2);
    hh[12] = 0.3731763325901154f * dz * (5.f*z2 - 3.f);
    hh[13] = 0.4570457994644657f * dx * (1.f - 5.f*z2);
    hh[14] = 1.445305721320277f * dz * (x2 - y2);
    hh[15] = 0.5900435899266435f * dx * (x2 - 3.f*y2);
    #pragma unroll
    for (int j = 0; j < 15; ++j) hh[16+j] = bo[1+j];

    // ---- head MLP: [31] -> relu[64] -> relu[64] -> sigmoid[3] ----
    float h1[HID];
    #pragma unroll
    for (int j = 0; j < HID; ++j) h1[j] = 0.f;
    #pragma unroll
    for (int k = 0; k < 31; ++k) {
        float e = hh[k];
        #pragma unroll
        for (int j = 0; j < HID; ++j)
            h1[j] = fmaf(e, wh1[k*HID+j], h1[j]);
    }
    #pragma unroll
    for (int j = 0; j < HID; ++j) h1[j] = fmaxf(h1[j], 0.f);

    float h2[HID];
    #pragma unroll
    for (int j = 0; j < HID; ++j) h2[j] = 0.f;
    #pragma unroll
    for (int k = 0; k < HID; ++k) {
        float e = h1[k];
        #pragma unroll
        for (int j = 0; j < HID; ++j)
            h2[j] = fmaf(e, wh2[k*HID+j], h2[j]);
    }
    #pragma unroll
    for (int j = 0; j < HID; ++j) h2[j] = fmaxf(h2[j], 0.f);

    float r0 = 0.f, r1 = 0.f, r2 = 0.f;
    #pragma unroll
    for (int k = 0; k < HID; ++k) {
        float e = h2[k];
        r0 = fmaf(e, wh3[k*3+0], r0);
        r1 = fmaf(e, wh3[k*3+1], r1);
        r2 = fmaf(e, wh3[k*3+2], r2);
    }
    r0 = 1.f / (1.f + expf(-r0));
    r1 = 1.f / (1.f + expf(-r1));
    r2 = 1.f / (1.f + expf(-r2));

    out[3*i+0] = r0;
    out[3*i+1] = r1;
    out[3*i+2] = r2;
    out[(size_t)3*n + i] = density;
}

// ---------------------------------------------------------------
// Fallback: proven fused kernel (used only if ws too small).
// ---------------------------------------------------------------
__global__ __launch_bounds__(256) void ngp_fused_kernel(
    const float* __restrict__ pos,
    const float* __restrict__ dirs,
    const float* __restrict__ aabb,
    const float* __restrict__ table,
    const float* __restrict__ wb1,
    const float* __restrict__ wb2,
    const float* __restrict__ wh1,
    const float* __restrict__ wh2,
    const float* __restrict__ wh3,
    float* __restrict__ out,
    int n, LevelParams lp)
{
    int i = blockIdx.x * blockDim.x + threadIdx.x;
    if (i >= n) return;

    float px = pos[3*i+0], py = pos[3*i+1], pz = pos[3*i+2];
    float mn0 = aabb[0], mn1 = aabb[1], mn2 = aabb[2];
    float mx0 = aabb[3], mx1 = aabb[4], mx2 = aabb[5];
    float x = (px - mn0) / (mx0 - mn0);
    float y = (py - mn1) / (mx1 - mn1);
    float z = (pz - mn2) / (mx2 - mn2);

    float enc[2*NLEV];
    #pragma unroll
    for (int l = 0; l < NLEV; ++l) {
        float s = lp.scale[l];
        unsigned res = lp.res[l];
        bool hashed = (lp.hashed_mask >> l) & 1u;
        float xs = fmaf(x, s, 0.5f);
        float ys = fmaf(y, s, 0.5f);
        float zs = fmaf(z, s, 0.5f);
        float fx = floorf(xs), fy = floorf(ys), fz = floorf(zs);
        float wx = xs - fx, wy = ys - fy, wz = zs - fz;
        unsigned ux = (unsigned)fx, uy = (unsigned)fy, uz = (unsigned)fz;
        const float2* tl = (const float2*)table + (size_t)l * TSZ;
        float a0 = 0.f, a1 = 0.f;
        #pragma unroll
        for (int c = 0; c < 8; ++c) {
            unsigned cx = ux + (c & 1);
            unsigned cy = uy + ((c >> 1) & 1);
            unsigned cz = uz + ((c >> 2) & 1);
            unsigned idx;
            if (hashed)
                idx = (cx ^ (cy * 2654435761u) ^ (cz * 805459861u)) & (TSZ - 1u);
            else
                idx = cx + cy * res + cz * res * res;
            float cw = ((c & 1) ? wx : 1.f - wx)
                     * (((c >> 1) & 1) ? wy : 1.f - wy)
                     * (((c >> 2) & 1) ? wz : 1.f - wz);
            float2 f = tl[idx];
            a0 = fmaf(f.x, cw, a0);
            a1 = fmaf(f.y, cw, a1);
        }
        enc[2*l]   = a0;
        enc[2*l+1] = a1;
    }

    float h[HID];
    #pragma unroll
    for (int j = 0; j < HID; ++j) h[j] = 0.f;
    #pragma unroll
    for (int k = 0; k < 2*NLEV; ++k) {
        float e = enc[k];
        #pragma unroll
        for (int j = 0; j < HID; ++j)
            h[j] = fmaf(e, wb1[k*HID+j], h[j]);
    }
    #pragma unroll
    for (int j = 0; j < HID; ++j) h[j] = fmaxf(h[j], 0.f);

    float bo[16];
    #pragma unroll
    for (int j = 0; j < 16; ++j) bo[j] = 0.f;
    #pragma unroll
    for (int k = 0; k < HID; ++k) {
        float e = h[k];
        #pragma unroll
        for (int j = 0; j < 16; ++j)
            bo[j] = fmaf(e, wb2[k*16+j], bo[j]);
    }
    float density = expf(bo[0] - 1.0f);

    float t0 = (dirs[3*i+0] + 1.f) * 0.5f;
    float t1 = (dirs[3*i+1] + 1.f) * 0.5f;
    float t2 = (dirs[3*i+2] + 1.f) * 0.5f;
    float dx = t0*2.f - 1.f, dy = t1*2.f - 1.f, dz = t2*2.f - 1.f;
    float x2 = dx*dx, y2 = dy*dy, z2 = dz*dz;
    float xy = dx*dy, xz = dx*dz, yz = dy*dz;
    float hh[31];
    hh[0]  = 0.28209479177387814f;
    hh[1]  = -0.48860251190291987f * dy;
    hh[2]  = 0.48860251190291987f * dz;
    hh[3]  = -0.48860251190291987f * dx;
    hh[4]  = 1.0925484305920792f * xy;
    hh[5]  = -1.0925484305920792f * yz;
    hh[6]  = 0.94617469575756f * z2 - 0.31539156525252f;
    hh[7]  = -1.0925484305920792f * xz;
    hh[8]  = 0.5462742152960396f * x2 - 0.5462742152960396f * y2;
    hh[9]  = 0.5900435899266435f * dy * (-3.f*x2 + y2);
    hh[10] = 2.890611442640554f * xy * dz;
    hh[11] = 0.4570457994644657f * dy * (1.f - 5.f*z2);
    hh[12] = 0.3731763325901154f * dz * (5.f*z2 - 3.f);
    hh[13] = 0.4570457994644657f * dx * (1.f - 5.f*z2);
    hh[14] = 1.445305721320277f * dz * (x2 - y2);
    hh[15] = 0.5900435899266435f * dx * (x2 - 3.f*y2);
    #pragma unroll
    for (int j = 0; j < 15; ++j) hh[16+j] = bo[1+j];

    float h1[HID];
    #pragma unroll
    for (int j = 0; j < HID; ++j) h1[j] = 0.f;
    #pragma unroll
    for (int k = 0; k < 31; ++k) {
        float e = hh[k];
        #pragma unroll
        for (int j = 0; j < HID; ++j)
            h1[j] = fmaf(e, wh1[k*HID+j], h1[j]);
    }
    #pragma unroll
    for (int j = 0; j < HID; ++j) h1[j] = fmaxf(h1[j], 0.f);

    float h2[HID];
    #pragma unroll
    for (int j = 0; j < HID; ++j) h2[j] = 0.f;
    #pragma unroll
    for (int k = 0; k < HID; ++k) {
        float e = h1[k];
        #pragma unroll
        for (int j = 0; j < HID; ++j)
            h2[j] = fmaf(e, wh2[k*HID+j], h2[j]);
    }
    #pragma unroll
    for (int j = 0; j < HID; ++j) h2[j] = fmaxf(h2[j], 0.f);

    float r0 = 0.f, r1 = 0.f, r2 = 0.f;
    #pragma unroll
    for (int k = 0; k < HID; ++k) {
        float e = h2[k];
        r0 = fmaf(e, wh3[k*3+0], r0);
        r1 = fmaf(e, wh3[k*3+1], r1);
        r2 = fmaf(e, wh3[k*3+2], r2);
    }
    r0 = 1.f / (1.f + expf(-r0));
    r1 = 1.f / (1.f + expf(-r1));
    r2 = 1.f / (1.f + expf(-r2));

    out[3*i+0] = r0;
    out[3*i+1] = r1;
    out[3*i+2] = r2;
    out[(size_t)3*n + i] = density;
}

extern "C" void kernel_launch(void* const* d_in, const int* in_sizes, int n_in,
                              void* d_out, int out_size, void* d_ws, size_t ws_size,
                              hipStream_t stream) {
    const float* pos   = (const float*)d_in[0];
    const float* dirs  = (const float*)d_in[1];
    const float* aabb  = (const float*)d_in[2];
    const float* table = (const float*)d_in[3];
    const float* wb1   = (const float*)d_in[4];
    const float* wb2   = (const float*)d_in[5];
    const float* wh1   = (const float*)d_in[6];
    const float* wh2   = (const float*)d_in[7];
    const float* wh3   = (const float*)d_in[8];
    float* out = (float*)d_out;
    int n = in_sizes[0] / 3;

    size_t enc_bytes = (size_t)2 * NLEV * n * sizeof(float);
    if (ws_size >= enc_bytes) {
        float* enc = (float*)d_ws;
        int total = n * NLEV;
        int grid1 = (total + 255) / 256;
        ngp_encode_kernel<<<grid1, 256, 0, stream>>>(pos, aabb, table, enc, n);
        int grid2 = (n + 255) / 256;
        ngp_mlp_kernel<<<grid2, 256, 0, stream>>>(enc, dirs, wb1, wb2, wh1, wh2,
                                                  wh3, out, n);
    } else {
        LevelParams lp;
        lp.hashed_mask = 0;
        double pls = exp((log(4096.0) - log(16.0)) / 15.0);
        for (int l = 0; l < NLEV; ++l) {
            double scale = 16.0 * pow(pls, (double)l) - 1.0;
            unsigned res = (unsigned)ceil(scale) + 1u;
            lp.scale[l] = (float)scale;
            lp.res[l] = res;
            if ((unsigned long long)res*(unsigned long long)res*(unsigned long long)res
                > (unsigned long long)TSZ)
                lp.hashed_mask |= (1u << l);
        }
        int block = 256;
        int grid = (n + block - 1) / block;
        ngp_fused_kernel<<<grid, block, 0, stream>>>(pos, dirs, aabb, table,
            wb1, wb2, wh1, wh2, wh3, out, n, lp);
    }
}

// Round 6
// 1123.516 us; speedup vs baseline: 7.9756x; 1.9180x over previous
//
#include <hip/hip_runtime.h>
#include <math.h>

namespace {
constexpr int NLEV = 16;
constexpr unsigned TSZ = 1u << 19;
constexpr int HID = 64;

// ws layout (ushort elements):
//   [0,2048)      WT1  [64][32]  = wb1^T   (base layer 1)
//   [2048,3072)   WT2  [16][64]  = wb2^T   (base layer 2)
//   [3072,5120)   WTh1 [64][32]  = wh1^T padded (k=31 row zero)
//   [5120,9216)   WTh2 [64][64]  = wh2^T
//   [9216,10240)  WTh3 [16][64]  = wh3^T padded (m=3..15 zero)
//   [16384, 16384+n*32)  enc bf16 [pt][32]
constexpr int OFF_WT1  = 0;
constexpr int OFF_WT2  = 2048;
constexpr int OFF_WTH1 = 3072;
constexpr int OFF_WTH2 = 5120;
constexpr int OFF_WTH3 = 9216;
constexpr int OFF_ENC  = 16384;

struct LevelParams {
    float scale[NLEV];
    unsigned res[NLEV];
    unsigned hashed_mask;
};

typedef short bf16x8 __attribute__((ext_vector_type(8)));
typedef float f32x4 __attribute__((ext_vector_type(4)));
} // namespace

__device__ inline unsigned short f2bf(float f) {
    union { float f; unsigned u; } v; v.f = f;
    unsigned r = v.u + 0x7fffu + ((v.u >> 16) & 1u);
    return (unsigned short)(r >> 16);
}
__device__ inline unsigned packrelu2(float a, float b) {
    a = fmaxf(a, 0.f); b = fmaxf(b, 0.f);
    return (unsigned)f2bf(a) | ((unsigned)f2bf(b) << 16);
}

// ---------------------------------------------------------------
// Weight prep: transpose + bf16-convert all MLP weights into ws.
// ---------------------------------------------------------------
__global__ void ngp_prep_weights(
    const float* __restrict__ wb1, const float* __restrict__ wb2,
    const float* __restrict__ wh1, const float* __restrict__ wh2,
    const float* __restrict__ wh3, unsigned short* __restrict__ W)
{
    int i = blockIdx.x * 256 + threadIdx.x;
    if (i >= 10240) return;
    float v; int o = i;
    if (o < 2048) {                      // WT1 [64][32]: wb1[k*64+m]
        int m = o >> 5, k = o & 31;
        v = wb1[k * 64 + m];
    } else if ((o -= 2048) < 1024) {     // WT2 [16][64]: wb2[k*16+m]
        int m = o >> 6, k = o & 63;
        v = wb2[k * 16 + m];
    } else if ((o -= 1024) < 2048) {     // WTh1 [64][32]: wh1[k*64+m], k<31
        int m = o >> 5, k = o & 31;
        v = (k < 31) ? wh1[k * 64 + m] : 0.f;
    } else if ((o -= 2048) < 4096) {     // WTh2 [64][64]: wh2[k*64+m]
        int m = o >> 6, k = o & 63;
        v = wh2[k * 64 + m];
    } else {                             // WTh3 [16][64]: wh3[k*3+m], m<3
        o -= 4096;
        int m = o >> 6, k = o & 63;
        v = (m < 3) ? wh3[k * 3 + m] : 0.f;
    }
    W[i] = f2bf(v);
}

// ---------------------------------------------------------------
// Pass 1: hash-grid encode. One thread per (point, level).
// Writes bf16 enc [pt][32] (one packed dword per thread).
// ---------------------------------------------------------------
__global__ __launch_bounds__(256) void ngp_encode_kernel(
    const float* __restrict__ pos,
    const float* __restrict__ aabb,
    const float* __restrict__ table,
    unsigned* __restrict__ enc_u32,   // [n][16] dwords = [n][32] bf16
    int n)
{
    int t = blockIdx.x * 256 + threadIdx.x;
    int p = t >> 4;
    int l = t & 15;
    if (p >= n) return;

    float mn0 = aabb[0], mn1 = aabb[1], mn2 = aabb[2];
    float mx0 = aabb[3], mx1 = aabb[4], mx2 = aabb[5];
    float x = (pos[3*p+0] - mn0) / (mx0 - mn0);
    float y = (pos[3*p+1] - mn1) / (mx1 - mn1);
    float z = (pos[3*p+2] - mn2) / (mx2 - mn2);

    // scale = 16 * (2^(8/15))^l - 1 = 2^(4 + 8l/15) - 1
    float s = exp2f(fmaf((float)l, 8.0f / 15.0f, 4.0f)) - 1.0f;
    unsigned res = (unsigned)ceilf(s) + 1u;
    bool hashed = (unsigned long long)res * res * res > (unsigned long long)TSZ;

    float xs = fmaf(x, s, 0.5f);
    float ys = fmaf(y, s, 0.5f);
    float zs = fmaf(z, s, 0.5f);
    float fx = floorf(xs), fy = floorf(ys), fz = floorf(zs);
    float wx = xs - fx, wy = ys - fy, wz = zs - fz;
    unsigned ux = (unsigned)fx, uy = (unsigned)fy, uz = (unsigned)fz;

    const float2* tl = (const float2*)table + (size_t)l * TSZ;
    float a0 = 0.f, a1 = 0.f;
    #pragma unroll
    for (int c = 0; c < 8; ++c) {
        unsigned cx = ux + (c & 1);
        unsigned cy = uy + ((c >> 1) & 1);
        unsigned cz = uz + ((c >> 2) & 1);
        unsigned idx;
        if (hashed)
            idx = (cx ^ (cy * 2654435761u) ^ (cz * 805459861u)) & (TSZ - 1u);
        else
            idx = cx + cy * res + cz * res * res;
        float cw = ((c & 1) ? wx : 1.f - wx)
                 * (((c >> 1) & 1) ? wy : 1.f - wy)
                 * (((c >> 2) & 1) ? wz : 1.f - wz);
        float2 f = tl[idx];
        a0 = fmaf(f.x, cw, a0);
        a1 = fmaf(f.y, cw, a1);
    }
    enc_u32[(size_t)p * 16 + l] = (unsigned)f2bf(a0) | ((unsigned)f2bf(a1) << 16);
}

// ---------------------------------------------------------------
// Pass 2: MFMA MLPs. 4 waves/block, each wave owns 64 points.
// M = hidden (rows), N = points (cols), so each layer's C feeds the
// next layer's B via a wave-private LDS [pt][hid] bf16 buffer.
// Frag mapping (16x16x32 bf16, m89/m97-verified):
//   A: lane = m + 16*kb  holds A[m][kb*8+j]      (row-major W^T read)
//   B: lane = n + 16*kb  holds B[kb*8+j][n]      (row-major [n][k] read)
//   C: col = lane&15, row = (lane>>4)*4 + reg
// ---------------------------------------------------------------
__global__ __launch_bounds__(256) void ngp_mlp_mfma_kernel(
    const unsigned short* __restrict__ W,
    const float* __restrict__ dirs,
    float* __restrict__ out,
    int n)
{
    const unsigned short* WT1  = W + OFF_WT1;
    const unsigned short* WT2  = W + OFF_WT2;
    const unsigned short* WTh1 = W + OFF_WTH1;
    const unsigned short* WTh2 = W + OFF_WTH2;
    const unsigned short* WTh3 = W + OFF_WTH3;
    const unsigned short* encb = W + OFF_ENC;

    __shared__ unsigned short Hbuf[4][64 * 72];   // [pt][64+pad] bf16
    __shared__ unsigned short HHbuf[4][64 * 40];  // [pt][32+pad] bf16

    const int wv = threadIdx.x >> 6;
    const int lane = threadIdx.x & 63;
    const int cc = lane & 15;   // B-col (pt within 16) / A-row (m within 16)
    const int kb = lane >> 4;   // k-octet / C row-group
    const int ptbase = (blockIdx.x * 4 + wv) * 64;

    unsigned short* Hs = Hbuf[wv];
    unsigned short* HH = HHbuf[wv];

    const f32x4 zero4 = {0.f, 0.f, 0.f, 0.f};

    // ===== GEMM1: h = relu(WT1[64x32] @ enc[32x64]) =====
    bf16x8 Be[4], A1[4];
    #pragma unroll
    for (int nt = 0; nt < 4; ++nt)
        Be[nt] = *(const bf16x8*)(encb + ((size_t)(ptbase + nt*16 + cc) << 5) + kb*8);
    #pragma unroll
    for (int mt = 0; mt < 4; ++mt)
        A1[mt] = *(const bf16x8*)(WT1 + (mt*16 + cc)*32 + kb*8);
    f32x4 acc[4][4];
    #pragma unroll
    for (int mt = 0; mt < 4; ++mt)
        #pragma unroll
        for (int nt = 0; nt < 4; ++nt)
            acc[mt][nt] = __builtin_amdgcn_mfma_f32_16x16x32_bf16(A1[mt], Be[nt], zero4, 0, 0, 0);
    #pragma unroll
    for (int mt = 0; mt < 4; ++mt)
        #pragma unroll
        for (int nt = 0; nt < 4; ++nt) {
            int pt = nt*16 + cc, hid = mt*16 + kb*4;
            *(uint2*)(Hs + pt*72 + hid) =
                make_uint2(packrelu2(acc[mt][nt][0], acc[mt][nt][1]),
                           packrelu2(acc[mt][nt][2], acc[mt][nt][3]));
        }

    // ===== GEMM2: bo = WT2[16x64] @ h[64x64]  (no activation) =====
    bf16x8 A2[2];
    #pragma unroll
    for (int ks = 0; ks < 2; ++ks)
        A2[ks] = *(const bf16x8*)(WT2 + cc*64 + ks*32 + kb*8);
    f32x4 acc2[4];
    #pragma unroll
    for (int nt = 0; nt < 4; ++nt) {
        bf16x8 b0 = *(const bf16x8*)(Hs + (nt*16 + cc)*72 +  0 + kb*8);
        bf16x8 b1 = *(const bf16x8*)(Hs + (nt*16 + cc)*72 + 32 + kb*8);
        acc2[nt] = __builtin_amdgcn_mfma_f32_16x16x32_bf16(A2[0], b0, zero4, 0, 0, 0);
        acc2[nt] = __builtin_amdgcn_mfma_f32_16x16x32_bf16(A2[1], b1, acc2[nt], 0, 0, 0);
    }

    // ===== SH encode (lane <-> point) into HH[pt][0..15] =====
    {
        int p = ptbase + lane;
        float t0 = (dirs[3*p+0] + 1.f) * 0.5f;
        float t1 = (dirs[3*p+1] + 1.f) * 0.5f;
        float t2 = (dirs[3*p+2] + 1.f) * 0.5f;
        float dx = t0*2.f - 1.f, dy = t1*2.f - 1.f, dz = t2*2.f - 1.f;
        float x2 = dx*dx, y2 = dy*dy, z2 = dz*dz;
        float xy = dx*dy, xz = dx*dz, yz = dy*dz;
        float sh[16];
        sh[0]  = 0.28209479177387814f;
        sh[1]  = -0.48860251190291987f * dy;
        sh[2]  = 0.48860251190291987f * dz;
        sh[3]  = -0.48860251190291987f * dx;
        sh[4]  = 1.0925484305920792f * xy;
        sh[5]  = -1.0925484305920792f * yz;
        sh[6]  = 0.94617469575756f * z2 - 0.31539156525252f;
        sh[7]  = -1.0925484305920792f * xz;
        sh[8]  = 0.5462742152960396f * x2 - 0.5462742152960396f * y2;
        sh[9]  = 0.5900435899266435f * dy * (-3.f*x2 + y2);
        sh[10] = 2.890611442640554f * xy * dz;
        sh[11] = 0.4570457994644657f * dy * (1.f - 5.f*z2);
        sh[12] = 0.3731763325901154f * dz * (5.f*z2 - 3.f);
        sh[13] = 0.4570457994644657f * dx * (1.f - 5.f*z2);
        sh[14] = 1.445305721320277f * dz * (x2 - y2);
        sh[15] = 0.5900435899266435f * dx * (x2 - 3.f*y2);
        unsigned u[8];
        #pragma unroll
        for (int j = 0; j < 8; ++j)
            u[j] = (unsigned)f2bf(sh[2*j]) | ((unsigned)f2bf(sh[2*j+1]) << 16);
        *(uint4*)(HH + lane*40)     = make_uint4(u[0], u[1], u[2], u[3]);
        *(uint4*)(HH + lane*40 + 8) = make_uint4(u[4], u[5], u[6], u[7]);
    }

    // geo -> HH[pt][16..30]; row 0 (density) parked in dead slot 31
    // (WTh1 row k=31 is zeroed, so hh[31] never contributes).
    #pragma unroll
    for (int nt = 0; nt < 4; ++nt) {
        int pt = nt*16 + cc;
        #pragma unroll
        for (int r = 0; r < 4; ++r) {
            int row = kb*4 + r;
            int slot = (row == 0) ? 31 : (15 + row);
            HH[pt*40 + slot] = f2bf(acc2[nt][r]);
        }
        if (kb == 0)
            out[(size_t)3*n + ptbase + pt] = expf(acc2[nt][0] - 1.0f);
    }

    // ===== GEMM3: h1 = relu(WTh1[64x32] @ hh[32x64]) =====
    bf16x8 A3[4], Bh[4];
    #pragma unroll
    for (int mt = 0; mt < 4; ++mt)
        A3[mt] = *(const bf16x8*)(WTh1 + (mt*16 + cc)*32 + kb*8);
    #pragma unroll
    for (int nt = 0; nt < 4; ++nt)
        Bh[nt] = *(const bf16x8*)(HH + (nt*16 + cc)*40 + kb*8);
    #pragma unroll
    for (int mt = 0; mt < 4; ++mt)
        #pragma unroll
        for (int nt = 0; nt < 4; ++nt)
            acc[mt][nt] = __builtin_amdgcn_mfma_f32_16x16x32_bf16(A3[mt], Bh[nt], zero4, 0, 0, 0);
    #pragma unroll
    for (int mt = 0; mt < 4; ++mt)
        #pragma unroll
        for (int nt = 0; nt < 4; ++nt) {
            int pt = nt*16 + cc, hid = mt*16 + kb*4;
            *(uint2*)(Hs + pt*72 + hid) =
                make_uint2(packrelu2(acc[mt][nt][0], acc[mt][nt][1]),
                           packrelu2(acc[mt][nt][2], acc[mt][nt][3]));
        }

    // ===== GEMM4: h2 = relu(WTh2[64x64] @ h1[64x64]) =====
    bf16x8 A4[4][2], B4[4][2];
    #pragma unroll
    for (int mt = 0; mt < 4; ++mt)
        #pragma unroll
        for (int ks = 0; ks < 2; ++ks)
            A4[mt][ks] = *(const bf16x8*)(WTh2 + (mt*16 + cc)*64 + ks*32 + kb*8);
    #pragma unroll
    for (int nt = 0; nt < 4; ++nt)
        #pragma unroll
        for (int ks = 0; ks < 2; ++ks)
            B4[nt][ks] = *(const bf16x8*)(Hs + (nt*16 + cc)*72 + ks*32 + kb*8);
    #pragma unroll
    for (int mt = 0; mt < 4; ++mt)
        #pragma unroll
        for (int nt = 0; nt < 4; ++nt) {
            acc[mt][nt] = __builtin_amdgcn_mfma_f32_16x16x32_bf16(A4[mt][0], B4[nt][0], zero4, 0, 0, 0);
            acc[mt][nt] = __builtin_amdgcn_mfma_f32_16x16x32_bf16(A4[mt][1], B4[nt][1], acc[mt][nt], 0, 0, 0);
        }
    #pragma unroll
    for (int mt = 0; mt < 4; ++mt)
        #pragma unroll
        for (int nt = 0; nt < 4; ++nt) {
            int pt = nt*16 + cc, hid = mt*16 + kb*4;
            *(uint2*)(Hs + pt*72 + hid) =
                make_uint2(packrelu2(acc[mt][nt][0], acc[mt][nt][1]),
                           packrelu2(acc[mt][nt][2], acc[mt][nt][3]));
        }

    // ===== GEMM5: rgb = sigmoid(WTh3[16x64] @ h2[64x64]), rows 0..2 =====
    bf16x8 A5[2];
    #pragma unroll
    for (int ks = 0; ks < 2; ++ks)
        A5[ks] = *(const bf16x8*)(WTh3 + cc*64 + ks*32 + kb*8);
    #pragma unroll
    for (int nt = 0; nt < 4; ++nt) {
        bf16x8 b0 = *(const bf16x8*)(Hs + (nt*16 + cc)*72 +  0 + kb*8);
        bf16x8 b1 = *(const bf16x8*)(Hs + (nt*16 + cc)*72 + 32 + kb*8);
        f32x4 a3 = __builtin_amdgcn_mfma_f32_16x16x32_bf16(A5[0], b0, zero4, 0, 0, 0);
        a3 = __builtin_amdgcn_mfma_f32_16x16x32_bf16(A5[1], b1, a3, 0, 0, 0);
        if (kb == 0) {
            size_t p = (size_t)(ptbase + nt*16 + cc);
            out[3*p + 0] = 1.f / (1.f + expf(-a3[0]));
            out[3*p + 1] = 1.f / (1.f + expf(-a3[1]));
            out[3*p + 2] = 1.f / (1.f + expf(-a3[2]));
        }
    }
}

// ---------------------------------------------------------------
// Fallback: proven fused scalar kernel (ws too small / odd n).
// ---------------------------------------------------------------
__global__ __launch_bounds__(256) void ngp_fused_kernel(
    const float* __restrict__ pos,
    const float* __restrict__ dirs,
    const float* __restrict__ aabb,
    const float* __restrict__ table,
    const float* __restrict__ wb1,
    const float* __restrict__ wb2,
    const float* __restrict__ wh1,
    const float* __restrict__ wh2,
    const float* __restrict__ wh3,
    float* __restrict__ out,
    int n, LevelParams lp)
{
    int i = blockIdx.x * blockDim.x + threadIdx.x;
    if (i >= n) return;

    float px = pos[3*i+0], py = pos[3*i+1], pz = pos[3*i+2];
    float mn0 = aabb[0], mn1 = aabb[1], mn2 = aabb[2];
    float mx0 = aabb[3], mx1 = aabb[4], mx2 = aabb[5];
    float x = (px - mn0) / (mx0 - mn0);
    float y = (py - mn1) / (mx1 - mn1);
    float z = (pz - mn2) / (mx2 - mn2);

    float enc[2*NLEV];
    #pragma unroll
    for (int l = 0; l < NLEV; ++l) {
        float s = lp.scale[l];
        unsigned res = lp.res[l];
        bool hashed = (lp.hashed_mask >> l) & 1u;
        float xs = fmaf(x, s, 0.5f);
        float ys = fmaf(y, s, 0.5f);
        float zs = fmaf(z, s, 0.5f);
        float fx = floorf(xs), fy = floorf(ys), fz = floorf(zs);
        float wx = xs - fx, wy = ys - fy, wz = zs - fz;
        unsigned ux = (unsigned)fx, uy = (unsigned)fy, uz = (unsigned)fz;
        const float2* tl = (const float2*)table + (size_t)l * TSZ;
        float a0 = 0.f, a1 = 0.f;
        #pragma unroll
        for (int c = 0; c < 8; ++c) {
            unsigned cx = ux + (c & 1);
            unsigned cy = uy + ((c >> 1) & 1);
            unsigned cz = uz + ((c >> 2) & 1);
            unsigned idx;
            if (hashed)
                idx = (cx ^ (cy * 2654435761u) ^ (cz * 805459861u)) & (TSZ - 1u);
            else
                idx = cx + cy * res + cz * res * res;
            float cw = ((c & 1) ? wx : 1.f - wx)
                     * (((c >> 1) & 1) ? wy : 1.f - wy)
                     * (((c >> 2) & 1) ? wz : 1.f - wz);
            float2 f = tl[idx];
            a0 = fmaf(f.x, cw, a0);
            a1 = fmaf(f.y, cw, a1);
        }
        enc[2*l]   = a0;
        enc[2*l+1] = a1;
    }

    float h[HID];
    #pragma unroll
    for (int j = 0; j < HID; ++j) h[j] = 0.f;
    #pragma unroll
    for (int k = 0; k < 2*NLEV; ++k) {
        float e = enc[k];
        #pragma unroll
        for (int j = 0; j < HID; ++j)
            h[j] = fmaf(e, wb1[k*HID+j], h[j]);
    }
    #pragma unroll
    for (int j = 0; j < HID; ++j) h[j] = fmaxf(h[j], 0.f);

    float bo[16];
    #pragma unroll
    for (int j = 0; j < 16; ++j) bo[j] = 0.f;
    #pragma unroll
    for (int k = 0; k < HID; ++k) {
        float e = h[k];
        #pragma unroll
        for (int j = 0; j < 16; ++j)
            bo[j] = fmaf(e, wb2[k*16+j], bo[j]);
    }
    float density = expf(bo[0] - 1.0f);

    float t0 = (dirs[3*i+0] + 1.f) * 0.5f;
    float t1 = (dirs[3*i+1] + 1.f) * 0.5f;
    float t2 = (dirs[3*i+2] + 1.f) * 0.5f;
    float dx = t0*2.f - 1.f, dy = t1*2.f - 1.f, dz = t2*2.f - 1.f;
    float x2 = dx*dx, y2 = dy*dy, z2 = dz*dz;
    float xy = dx*dy, xz = dx*dz, yz = dy*dz;
    float hh[31];
    hh[0]  = 0.28209479177387814f;
    hh[1]  = -0.48860251190291987f * dy;
    hh[2]  = 0.48860251190291987f * dz;
    hh[3]  = -0.48860251190291987f * dx;
    hh[4]  = 1.0925484305920792f * xy;
    hh[5]  = -1.0925484305920792f * yz;
    hh[6]  = 0.94617469575756f * z2 - 0.31539156525252f;
    hh[7]  = -1.0925484305920792f * xz;
    hh[8]  = 0.5462742152960396f * x2 - 0.5462742152960396f * y2;
    hh[9]  = 0.5900435899266435f * dy * (-3.f*x2 + y2);
    hh[10] = 2.890611442640554f * xy * dz;
    hh[11] = 0.4570457994644657f * dy * (1.f - 5.f*z2);
    hh[12] = 0.3731763325901154f * dz * (5.f*z2 - 3.f);
    hh[13] = 0.4570457994644657f * dx * (1.f - 5.f*z2);
    hh[14] = 1.445305721320277f * dz * (x2 - y2);
    hh[15] = 0.5900435899266435f * dx * (x2 - 3.f*y2);
    #pragma unroll
    for (int j = 0; j < 15; ++j) hh[16+j] = bo[1+j];

    float h1[HID];
    #pragma unroll
    for (int j = 0; j < HID; ++j) h1[j] = 0.f;
    #pragma unroll
    for (int k = 0; k < 31; ++k) {
        float e = hh[k];
        #pragma unroll
        for (int j = 0; j < HID; ++j)
            h1[j] = fmaf(e, wh1[k*HID+j], h1[j]);
    }
    #pragma unroll
    for (int j = 0; j < HID; ++j) h1[j] = fmaxf(h1[j], 0.f);

    float h2[HID];
    #pragma unroll
    for (int j = 0; j < HID; ++j) h2[j] = 0.f;
    #pragma unroll
    for (int k = 0; k < HID; ++k) {
        float e = h1[k];
        #pragma unroll
        for (int j = 0; j < HID; ++j)
            h2[j] = fmaf(e, wh2[k*HID+j], h2[j]);
    }
    #pragma unroll
    for (int j = 0; j < HID; ++j) h2[j] = fmaxf(h2[j], 0.f);

    float r0 = 0.f, r1 = 0.f, r2 = 0.f;
    #pragma unroll
    for (int k = 0; k < HID; ++k) {
        float e = h2[k];
        r0 = fmaf(e, wh3[k*3+0], r0);
        r1 = fmaf(e, wh3[k*3+1], r1);
        r2 = fmaf(e, wh3[k*3+2], r2);
    }
    r0 = 1.f / (1.f + expf(-r0));
    r1 = 1.f / (1.f + expf(-r1));
    r2 = 1.f / (1.f + expf(-r2));

    out[3*i+0] = r0;
    out[3*i+1] = r1;
    out[3*i+2] = r2;
    out[(size_t)3*n + i] = density;
}

extern "C" void kernel_launch(void* const* d_in, const int* in_sizes, int n_in,
                              void* d_out, int out_size, void* d_ws, size_t ws_size,
                              hipStream_t stream) {
    const float* pos   = (const float*)d_in[0];
    const float* dirs  = (const float*)d_in[1];
    const float* aabb  = (const float*)d_in[2];
    const float* table = (const float*)d_in[3];
    const float* wb1   = (const float*)d_in[4];
    const float* wb2   = (const float*)d_in[5];
    const float* wh1   = (const float*)d_in[6];
    const float* wh2   = (const float*)d_in[7];
    const float* wh3   = (const float*)d_in[8];
    float* out = (float*)d_out;
    int n = in_sizes[0] / 3;

    size_t need = (size_t)OFF_ENC * 2 + (size_t)n * 64;
    if (ws_size >= need && (n & 255) == 0) {
        unsigned short* W = (unsigned short*)d_ws;
        ngp_prep_weights<<<40, 256, 0, stream>>>(wb1, wb2, wh1, wh2, wh3, W);
        int total = n * NLEV;
        ngp_encode_kernel<<<(total + 255) / 256, 256, 0, stream>>>(
            pos, aabb, table, (unsigned*)(W + OFF_ENC), n);
        ngp_mlp_mfma_kernel<<<n / 256, 256, 0, stream>>>(W, dirs, out, n);
    } else {
        LevelParams lp;
        lp.hashed_mask = 0;
        double pls = exp((log(4096.0) - log(16.0)) / 15.0);
        for (int l = 0; l < NLEV; ++l) {
            double scale = 16.0 * pow(pls, (double)l) - 1.0;
            unsigned res = (unsigned)ceil(scale) + 1u;
            lp.scale[l] = (float)scale;
            lp.res[l] = res;
            if ((unsigned long long)res*(unsigned long long)res*(unsigned long long)res
                > (unsigned long long)TSZ)
                lp.hashed_mask |= (1u << l);
        }
        int block = 256;
        int grid = (n + block - 1) / block;
        ngp_fused_kernel<<<grid, block, 0, stream>>>(pos, dirs, aabb, table,
            wb1, wb2, wh1, wh2, wh3, out, n, lp);
    }
}

// Round 7
// 583.457 us; speedup vs baseline: 15.3581x; 1.9256x over previous
//
#include <hip/hip_runtime.h>
#include <math.h>

namespace {
constexpr int NLEV = 16;
constexpr unsigned TSZ = 1u << 19;
constexpr int HID = 64;

// ws layout (ushort elements):
//   [0,16384)            weights (see below)
//   [16384, 16384+n*32)  enc bf16, layout [16 levels][n] dwords
//   [16384+n*32, ...)    bf16-packed table [16][TSZ] dwords (optional)
constexpr int OFF_WT1  = 0;
constexpr int OFF_WT2  = 2048;
constexpr int OFF_WTH1 = 3072;
constexpr int OFF_WTH2 = 5120;
constexpr int OFF_WTH3 = 9216;
constexpr int OFF_ENC  = 16384;

struct LevelParams {
    float scale[NLEV];
    unsigned res[NLEV];
    unsigned hashed_mask;
};

typedef short bf16x8 __attribute__((ext_vector_type(8)));
typedef float f32x4 __attribute__((ext_vector_type(4)));
} // namespace

__device__ inline unsigned short f2bf(float f) {
    union { float f; unsigned u; } v; v.f = f;
    unsigned r = v.u + 0x7fffu + ((v.u >> 16) & 1u);
    return (unsigned short)(r >> 16);
}
__device__ inline float bf2f(unsigned hi16) {
    union { unsigned u; float f; } v; v.u = hi16 << 16;
    return v.f;
}
__device__ inline unsigned packrelu2(float a, float b) {
    a = fmaxf(a, 0.f); b = fmaxf(b, 0.f);
    return (unsigned)f2bf(a) | ((unsigned)f2bf(b) << 16);
}

// ---------------------------------------------------------------
// Weight prep: transpose + bf16-convert all MLP weights into ws.
// ---------------------------------------------------------------
__global__ void ngp_prep_weights(
    const float* __restrict__ wb1, const float* __restrict__ wb2,
    const float* __restrict__ wh1, const float* __restrict__ wh2,
    const float* __restrict__ wh3, unsigned short* __restrict__ W)
{
    int i = blockIdx.x * 256 + threadIdx.x;
    if (i >= 10240) return;
    float v; int o = i;
    if (o < 2048) {                      // WT1 [64][32]: wb1[k*64+m]
        int m = o >> 5, k = o & 31;
        v = wb1[k * 64 + m];
    } else if ((o -= 2048) < 1024) {     // WT2 [16][64]: wb2[k*16+m]
        int m = o >> 6, k = o & 63;
        v = wb2[k * 16 + m];
    } else if ((o -= 1024) < 2048) {     // WTh1 [64][32]: wh1[k*64+m], k<31
        int m = o >> 5, k = o & 31;
        v = (k < 31) ? wh1[k * 64 + m] : 0.f;
    } else if ((o -= 2048) < 4096) {     // WTh2 [64][64]: wh2[k*64+m]
        int m = o >> 6, k = o & 63;
        v = wh2[k * 64 + m];
    } else {                             // WTh3 [16][64]: wh3[k*3+m], m<3
        o -= 4096;
        int m = o >> 6, k = o & 63;
        v = (m < 3) ? wh3[k * 3 + m] : 0.f;
    }
    W[i] = f2bf(v);
}

// ---------------------------------------------------------------
// Table conversion: f32 float2 -> packed bf16x2 (one dword/entry).
// ---------------------------------------------------------------
__global__ __launch_bounds__(256) void ngp_conv_table(
    const float2* __restrict__ table, unsigned* __restrict__ tbl_bf)
{
    size_t i = (size_t)blockIdx.x * 256 + threadIdx.x;
    float2 f = table[i];
    tbl_bf[i] = (unsigned)f2bf(f.x) | ((unsigned)f2bf(f.y) << 16);
}

// ---------------------------------------------------------------
// Pass 1: hash-grid encode, LEVEL-MAJOR. Block = 256 points of ONE
// level; grid ordered level-slowest so concurrently-resident blocks
// share one level's table (fits per-XCD L2: 2 MB bf16 / 4 MB f32).
// enc layout: [level][point] dwords (coalesced writes).
// ---------------------------------------------------------------
__global__ __launch_bounds__(256) void ngp_encode_lm_kernel(
    const float* __restrict__ pos,
    const float* __restrict__ aabb,
    const float2* __restrict__ tbl_f32,
    const unsigned* __restrict__ tbl_bf,
    int use_bf16,
    unsigned* __restrict__ enc_u32,   // [16][n] dwords
    int n)
{
    int bpl = n >> 8;                  // blocks per level
    int l = blockIdx.x / bpl;
    int p = (blockIdx.x - l * bpl) * 256 + threadIdx.x;

    float mn0 = aabb[0], mn1 = aabb[1], mn2 = aabb[2];
    float mx0 = aabb[3], mx1 = aabb[4], mx2 = aabb[5];
    float x = (pos[3*p+0] - mn0) / (mx0 - mn0);
    float y = (pos[3*p+1] - mn1) / (mx1 - mn1);
    float z = (pos[3*p+2] - mn2) / (mx2 - mn2);

    // scale = 16 * (2^(8/15))^l - 1 = 2^(4 + 8l/15) - 1
    float s = exp2f(fmaf((float)l, 8.0f / 15.0f, 4.0f)) - 1.0f;
    unsigned res = (unsigned)ceilf(s) + 1u;
    bool hashed = (unsigned long long)res * res * res > (unsigned long long)TSZ;

    float xs = fmaf(x, s, 0.5f);
    float ys = fmaf(y, s, 0.5f);
    float zs = fmaf(z, s, 0.5f);
    float fx = floorf(xs), fy = floorf(ys), fz = floorf(zs);
    float wx = xs - fx, wy = ys - fy, wz = zs - fz;
    unsigned ux = (unsigned)fx, uy = (unsigned)fy, uz = (unsigned)fz;

    unsigned idxs[8];
    float cws[8];
    #pragma unroll
    for (int c = 0; c < 8; ++c) {
        unsigned cx = ux + (c & 1);
        unsigned cy = uy + ((c >> 1) & 1);
        unsigned cz = uz + ((c >> 2) & 1);
        if (hashed)
            idxs[c] = (cx ^ (cy * 2654435761u) ^ (cz * 805459861u)) & (TSZ - 1u);
        else
            idxs[c] = cx + cy * res + cz * res * res;
        cws[c] = ((c & 1) ? wx : 1.f - wx)
               * (((c >> 1) & 1) ? wy : 1.f - wy)
               * (((c >> 2) & 1) ? wz : 1.f - wz);
    }

    float a0 = 0.f, a1 = 0.f;
    if (use_bf16) {
        const unsigned* tl = tbl_bf + (size_t)l * TSZ;
        #pragma unroll
        for (int c = 0; c < 8; ++c) {
            unsigned e = tl[idxs[c]];
            a0 = fmaf(bf2f(e & 0xffffu), cws[c], a0);
            a1 = fmaf(bf2f(e >> 16), cws[c], a1);
        }
    } else {
        const float2* tl = tbl_f32 + (size_t)l * TSZ;
        #pragma unroll
        for (int c = 0; c < 8; ++c) {
            float2 f = tl[idxs[c]];
            a0 = fmaf(f.x, cws[c], a0);
            a1 = fmaf(f.y, cws[c], a1);
        }
    }
    enc_u32[(size_t)l * n + p] = (unsigned)f2bf(a0) | ((unsigned)f2bf(a1) << 16);
}

// ---------------------------------------------------------------
// Pass 2: MFMA MLPs. 4 waves/block, each wave owns 64 points.
// enc is [level][point] dwords -> B-frag = 4 coalesced dword loads.
// Frag mapping (16x16x32 bf16, m89/m97-verified):
//   A: lane = m + 16*kb  holds A[m][kb*8+j]
//   B: lane = n + 16*kb  holds B[kb*8+j][n]
//   C: col = lane&15, row = (lane>>4)*4 + reg
// ---------------------------------------------------------------
__global__ __launch_bounds__(256) void ngp_mlp_mfma_kernel(
    const unsigned short* __restrict__ W,
    const float* __restrict__ dirs,
    float* __restrict__ out,
    int n)
{
    const unsigned short* WT1  = W + OFF_WT1;
    const unsigned short* WT2  = W + OFF_WT2;
    const unsigned short* WTh1 = W + OFF_WTH1;
    const unsigned short* WTh2 = W + OFF_WTH2;
    const unsigned short* WTh3 = W + OFF_WTH3;
    const unsigned* encb = (const unsigned*)(W + OFF_ENC);

    __shared__ unsigned short Hbuf[4][64 * 72];   // [pt][64+pad] bf16
    __shared__ unsigned short HHbuf[4][64 * 40];  // [pt][32+pad] bf16

    const int wv = threadIdx.x >> 6;
    const int lane = threadIdx.x & 63;
    const int cc = lane & 15;
    const int kb = lane >> 4;
    const int ptbase = (blockIdx.x * 4 + wv) * 64;

    unsigned short* Hs = Hbuf[wv];
    unsigned short* HH = HHbuf[wv];

    const f32x4 zero4 = {0.f, 0.f, 0.f, 0.f};

    // ===== GEMM1: h = relu(WT1[64x32] @ enc[32x64]) =====
    bf16x8 Be[4], A1[4];
    #pragma unroll
    for (int nt = 0; nt < 4; ++nt) {
        union { unsigned u[4]; bf16x8 v; } uu;
        int p = ptbase + nt*16 + cc;
        #pragma unroll
        for (int q = 0; q < 4; ++q)
            uu.u[q] = encb[(size_t)(kb*4 + q) * n + p];
        Be[nt] = uu.v;
    }
    #pragma unroll
    for (int mt = 0; mt < 4; ++mt)
        A1[mt] = *(const bf16x8*)(WT1 + (mt*16 + cc)*32 + kb*8);
    f32x4 acc[4][4];
    #pragma unroll
    for (int mt = 0; mt < 4; ++mt)
        #pragma unroll
        for (int nt = 0; nt < 4; ++nt)
            acc[mt][nt] = __builtin_amdgcn_mfma_f32_16x16x32_bf16(A1[mt], Be[nt], zero4, 0, 0, 0);
    #pragma unroll
    for (int mt = 0; mt < 4; ++mt)
        #pragma unroll
        for (int nt = 0; nt < 4; ++nt) {
            int pt = nt*16 + cc, hid = mt*16 + kb*4;
            *(uint2*)(Hs + pt*72 + hid) =
                make_uint2(packrelu2(acc[mt][nt][0], acc[mt][nt][1]),
                           packrelu2(acc[mt][nt][2], acc[mt][nt][3]));
        }

    // ===== GEMM2: bo = WT2[16x64] @ h[64x64]  (no activation) =====
    bf16x8 A2[2];
    #pragma unroll
    for (int ks = 0; ks < 2; ++ks)
        A2[ks] = *(const bf16x8*)(WT2 + cc*64 + ks*32 + kb*8);
    f32x4 acc2[4];
    #pragma unroll
    for (int nt = 0; nt < 4; ++nt) {
        bf16x8 b0 = *(const bf16x8*)(Hs + (nt*16 + cc)*72 +  0 + kb*8);
        bf16x8 b1 = *(const bf16x8*)(Hs + (nt*16 + cc)*72 + 32 + kb*8);
        acc2[nt] = __builtin_amdgcn_mfma_f32_16x16x32_bf16(A2[0], b0, zero4, 0, 0, 0);
        acc2[nt] = __builtin_amdgcn_mfma_f32_16x16x32_bf16(A2[1], b1, acc2[nt], 0, 0, 0);
    }

    // ===== SH encode (lane <-> point) into HH[pt][0..15] =====
    {
        int p = ptbase + lane;
        float t0 = (dirs[3*p+0] + 1.f) * 0.5f;
        float t1 = (dirs[3*p+1] + 1.f) * 0.5f;
        float t2 = (dirs[3*p+2] + 1.f) * 0.5f;
        float dx = t0*2.f - 1.f, dy = t1*2.f - 1.f, dz = t2*2.f - 1.f;
        float x2 = dx*dx, y2 = dy*dy, z2 = dz*dz;
        float xy = dx*dy, xz = dx*dz, yz = dy*dz;
        float sh[16];
        sh[0]  = 0.28209479177387814f;
        sh[1]  = -0.48860251190291987f * dy;
        sh[2]  = 0.48860251190291987f * dz;
        sh[3]  = -0.48860251190291987f * dx;
        sh[4]  = 1.0925484305920792f * xy;
        sh[5]  = -1.0925484305920792f * yz;
        sh[6]  = 0.94617469575756f * z2 - 0.31539156525252f;
        sh[7]  = -1.0925484305920792f * xz;
        sh[8]  = 0.5462742152960396f * x2 - 0.5462742152960396f * y2;
        sh[9]  = 0.5900435899266435f * dy * (-3.f*x2 + y2);
        sh[10] = 2.890611442640554f * xy * dz;
        sh[11] = 0.4570457994644657f * dy * (1.f - 5.f*z2);
        sh[12] = 0.3731763325901154f * dz * (5.f*z2 - 3.f);
        sh[13] = 0.4570457994644657f * dx * (1.f - 5.f*z2);
        sh[14] = 1.445305721320277f * dz * (x2 - y2);
        sh[15] = 0.5900435899266435f * dx * (x2 - 3.f*y2);
        unsigned u[8];
        #pragma unroll
        for (int j = 0; j < 8; ++j)
            u[j] = (unsigned)f2bf(sh[2*j]) | ((unsigned)f2bf(sh[2*j+1]) << 16);
        *(uint4*)(HH + lane*40)     = make_uint4(u[0], u[1], u[2], u[3]);
        *(uint4*)(HH + lane*40 + 8) = make_uint4(u[4], u[5], u[6], u[7]);
    }

    // geo -> HH[pt][16..30]; row 0 (density) parked in dead slot 31
    // (WTh1 row k=31 is zeroed, so hh[31] never contributes).
    #pragma unroll
    for (int nt = 0; nt < 4; ++nt) {
        int pt = nt*16 + cc;
        #pragma unroll
        for (int r = 0; r < 4; ++r) {
            int row = kb*4 + r;
            int slot = (row == 0) ? 31 : (15 + row);
            HH[pt*40 + slot] = f2bf(acc2[nt][r]);
        }
        if (kb == 0)
            out[(size_t)3*n + ptbase + pt] = expf(acc2[nt][0] - 1.0f);
    }

    // ===== GEMM3: h1 = relu(WTh1[64x32] @ hh[32x64]) =====
    bf16x8 A3[4], Bh[4];
    #pragma unroll
    for (int mt = 0; mt < 4; ++mt)
        A3[mt] = *(const bf16x8*)(WTh1 + (mt*16 + cc)*32 + kb*8);
    #pragma unroll
    for (int nt = 0; nt < 4; ++nt)
        Bh[nt] = *(const bf16x8*)(HH + (nt*16 + cc)*40 + kb*8);
    #pragma unroll
    for (int mt = 0; mt < 4; ++mt)
        #pragma unroll
        for (int nt = 0; nt < 4; ++nt)
            acc[mt][nt] = __builtin_amdgcn_mfma_f32_16x16x32_bf16(A3[mt], Bh[nt], zero4, 0, 0, 0);
    #pragma unroll
    for (int mt = 0; mt < 4; ++mt)
        #pragma unroll
        for (int nt = 0; nt < 4; ++nt) {
            int pt = nt*16 + cc, hid = mt*16 + kb*4;
            *(uint2*)(Hs + pt*72 + hid) =
                make_uint2(packrelu2(acc[mt][nt][0], acc[mt][nt][1]),
                           packrelu2(acc[mt][nt][2], acc[mt][nt][3]));
        }

    // ===== GEMM4: h2 = relu(WTh2[64x64] @ h1[64x64]) =====
    bf16x8 A4[4][2], B4[4][2];
    #pragma unroll
    for (int mt = 0; mt < 4; ++mt)
        #pragma unroll
        for (int ks = 0; ks < 2; ++ks)
            A4[mt][ks] = *(const bf16x8*)(WTh2 + (mt*16 + cc)*64 + ks*32 + kb*8);
    #pragma unroll
    for (int nt = 0; nt < 4; ++nt)
        #pragma unroll
        for (int ks = 0; ks < 2; ++ks)
            B4[nt][ks] = *(const bf16x8*)(Hs + (nt*16 + cc)*72 + ks*32 + kb*8);
    #pragma unroll
    for (int mt = 0; mt < 4; ++mt)
        #pragma unroll
        for (int nt = 0; nt < 4; ++nt) {
            acc[mt][nt] = __builtin_amdgcn_mfma_f32_16x16x32_bf16(A4[mt][0], B4[nt][0], zero4, 0, 0, 0);
            acc[mt][nt] = __builtin_amdgcn_mfma_f32_16x16x32_bf16(A4[mt][1], B4[nt][1], acc[mt][nt], 0, 0, 0);
        }
    #pragma unroll
    for (int mt = 0; mt < 4; ++mt)
        #pragma unroll
        for (int nt = 0; nt < 4; ++nt) {
            int pt = nt*16 + cc, hid = mt*16 + kb*4;
            *(uint2*)(Hs + pt*72 + hid) =
                make_uint2(packrelu2(acc[mt][nt][0], acc[mt][nt][1]),
                           packrelu2(acc[mt][nt][2], acc[mt][nt][3]));
        }

    // ===== GEMM5: rgb = sigmoid(WTh3[16x64] @ h2[64x64]), rows 0..2 =====
    bf16x8 A5[2];
    #pragma unroll
    for (int ks = 0; ks < 2; ++ks)
        A5[ks] = *(const bf16x8*)(WTh3 + cc*64 + ks*32 + kb*8);
    #pragma unroll
    for (int nt = 0; nt < 4; ++nt) {
        bf16x8 b0 = *(const bf16x8*)(Hs + (nt*16 + cc)*72 +  0 + kb*8);
        bf16x8 b1 = *(const bf16x8*)(Hs + (nt*16 + cc)*72 + 32 + kb*8);
        f32x4 a3 = __builtin_amdgcn_mfma_f32_16x16x32_bf16(A5[0], b0, zero4, 0, 0, 0);
        a3 = __builtin_amdgcn_mfma_f32_16x16x32_bf16(A5[1], b1, a3, 0, 0, 0);
        if (kb == 0) {
            size_t p = (size_t)(ptbase + nt*16 + cc);
            out[3*p + 0] = 1.f / (1.f + expf(-a3[0]));
            out[3*p + 1] = 1.f / (1.f + expf(-a3[1]));
            out[3*p + 2] = 1.f / (1.f + expf(-a3[2]));
        }
    }
}

// ---------------------------------------------------------------
// Fallback: proven fused scalar kernel (ws too small / odd n).
// ---------------------------------------------------------------
__global__ __launch_bounds__(256) void ngp_fused_kernel(
    const float* __restrict__ pos,
    const float* __restrict__ dirs,
    const float* __restrict__ aabb,
    const float* __restrict__ table,
    const float* __restrict__ wb1,
    const float* __restrict__ wb2,
    const float* __restrict__ wh1,
    const float* __restrict__ wh2,
    const float* __restrict__ wh3,
    float* __restrict__ out,
    int n, LevelParams lp)
{
    int i = blockIdx.x * blockDim.x + threadIdx.x;
    if (i >= n) return;

    float px = pos[3*i+0], py = pos[3*i+1], pz = pos[3*i+2];
    float mn0 = aabb[0], mn1 = aabb[1], mn2 = aabb[2];
    float mx0 = aabb[3], mx1 = aabb[4], mx2 = aabb[5];
    float x = (px - mn0) / (mx0 - mn0);
    float y = (py - mn1) / (mx1 - mn1);
    float z = (pz - mn2) / (mx2 - mn2);

    float enc[2*NLEV];
    #pragma unroll
    for (int l = 0; l < NLEV; ++l) {
        float s = lp.scale[l];
        unsigned res = lp.res[l];
        bool hashed = (lp.hashed_mask >> l) & 1u;
        float xs = fmaf(x, s, 0.5f);
        float ys = fmaf(y, s, 0.5f);
        float zs = fmaf(z, s, 0.5f);
        float fx = floorf(xs), fy = floorf(ys), fz = floorf(zs);
        float wx = xs - fx, wy = ys - fy, wz = zs - fz;
        unsigned ux = (unsigned)fx, uy = (unsigned)fy, uz = (unsigned)fz;
        const float2* tl = (const float2*)table + (size_t)l * TSZ;
        float a0 = 0.f, a1 = 0.f;
        #pragma unroll
        for (int c = 0; c < 8; ++c) {
            unsigned cx = ux + (c & 1);
            unsigned cy = uy + ((c >> 1) & 1);
            unsigned cz = uz + ((c >> 2) & 1);
            unsigned idx;
            if (hashed)
                idx = (cx ^ (cy * 2654435761u) ^ (cz * 805459861u)) & (TSZ - 1u);
            else
                idx = cx + cy * res + cz * res * res;
            float cw = ((c & 1) ? wx : 1.f - wx)
                     * (((c >> 1) & 1) ? wy : 1.f - wy)
                     * (((c >> 2) & 1) ? wz : 1.f - wz);
            float2 f = tl[idx];
            a0 = fmaf(f.x, cw, a0);
            a1 = fmaf(f.y, cw, a1);
        }
        enc[2*l]   = a0;
        enc[2*l+1] = a1;
    }

    float h[HID];
    #pragma unroll
    for (int j = 0; j < HID; ++j) h[j] = 0.f;
    #pragma unroll
    for (int k = 0; k < 2*NLEV; ++k) {
        float e = enc[k];
        #pragma unroll
        for (int j = 0; j < HID; ++j)
            h[j] = fmaf(e, wb1[k*HID+j], h[j]);
    }
    #pragma unroll
    for (int j = 0; j < HID; ++j) h[j] = fmaxf(h[j], 0.f);

    float bo[16];
    #pragma unroll
    for (int j = 0; j < 16; ++j) bo[j] = 0.f;
    #pragma unroll
    for (int k = 0; k < HID; ++k) {
        float e = h[k];
        #pragma unroll
        for (int j = 0; j < 16; ++j)
            bo[j] = fmaf(e, wb2[k*16+j], bo[j]);
    }
    float density = expf(bo[0] - 1.0f);

    float t0 = (dirs[3*i+0] + 1.f) * 0.5f;
    float t1 = (dirs[3*i+1] + 1.f) * 0.5f;
    float t2 = (dirs[3*i+2] + 1.f) * 0.5f;
    float dx = t0*2.f - 1.f, dy = t1*2.f - 1.f, dz = t2*2.f - 1.f;
    float x2 = dx*dx, y2 = dy*dy, z2 = dz*dz;
    float xy = dx*dy, xz = dx*dz, yz = dy*dz;
    float hh[31];
    hh[0]  = 0.28209479177387814f;
    hh[1]  = -0.48860251190291987f * dy;
    hh[2]  = 0.48860251190291987f * dz;
    hh[3]  = -0.48860251190291987f * dx;
    hh[4]  = 1.0925484305920792f * xy;
    hh[5]  = -1.0925484305920792f * yz;
    hh[6]  = 0.94617469575756f * z2 - 0.31539156525252f;
    hh[7]  = -1.0925484305920792f * xz;
    hh[8]  = 0.5462742152960396f * x2 - 0.5462742152960396f * y2;
    hh[9]  = 0.5900435899266435f * dy * (-3.f*x2 + y2);
    hh[10] = 2.890611442640554f * xy * dz;
    hh[11] = 0.4570457994644657f * dy * (1.f - 5.f*z2);
    hh[12] = 0.3731763325901154f * dz * (5.f*z2 - 3.f);
    hh[13] = 0.4570457994644657f * dx * (1.f - 5.f*z2);
    hh[14] = 1.445305721320277f * dz * (x2 - y2);
    hh[15] = 0.5900435899266435f * dx * (x2 - 3.f*y2);
    #pragma unroll
    for (int j = 0; j < 15; ++j) hh[16+j] = bo[1+j];

    float h1[HID];
    #pragma unroll
    for (int j = 0; j < HID; ++j) h1[j] = 0.f;
    #pragma unroll
    for (int k = 0; k < 31; ++k) {
        float e = hh[k];
        #pragma unroll
        for (int j = 0; j < HID; ++j)
            h1[j] = fmaf(e, wh1[k*HID+j], h1[j]);
    }
    #pragma unroll
    for (int j = 0; j < HID; ++j) h1[j] = fmaxf(h1[j], 0.f);

    float h2[HID];
    #pragma unroll
    for (int j = 0; j < HID; ++j) h2[j] = 0.f;
    #pragma unroll
    for (int k = 0; k < HID; ++k) {
        float e = h1[k];
        #pragma unroll
        for (int j = 0; j < HID; ++j)
            h2[j] = fmaf(e, wh2[k*HID+j], h2[j]);
    }
    #pragma unroll
    for (int j = 0; j < HID; ++j) h2[j] = fmaxf(h2[j], 0.f);

    float r0 = 0.f, r1 = 0.f, r2 = 0.f;
    #pragma unroll
    for (int k = 0; k < HID; ++k) {
        float e = h2[k];
        r0 = fmaf(e, wh3[k*3+0], r0);
        r1 = fmaf(e, wh3[k*3+1], r1);
        r2 = fmaf(e, wh3[k*3+2], r2);
    }
    r0 = 1.f / (1.f + expf(-r0));
    r1 = 1.f / (1.f + expf(-r1));
    r2 = 1.f / (1.f + expf(-r2));

    out[3*i+0] = r0;
    out[3*i+1] = r1;
    out[3*i+2] = r2;
    out[(size_t)3*n + i] = density;
}

extern "C" void kernel_launch(void* const* d_in, const int* in_sizes, int n_in,
                              void* d_out, int out_size, void* d_ws, size_t ws_size,
                              hipStream_t stream) {
    const float* pos   = (const float*)d_in[0];
    const float* dirs  = (const float*)d_in[1];
    const float* aabb  = (const float*)d_in[2];
    const float* table = (const float*)d_in[3];
    const float* wb1   = (const float*)d_in[4];
    const float* wb2   = (const float*)d_in[5];
    const float* wh1   = (const float*)d_in[6];
    const float* wh2   = (const float*)d_in[7];
    const float* wh3   = (const float*)d_in[8];
    float* out = (float*)d_out;
    int n = in_sizes[0] / 3;

    size_t need_basic = 32768 + (size_t)n * 64;                      // weights + enc
    size_t need_full  = need_basic + (size_t)NLEV * TSZ * 4;         // + bf16 table
    if (ws_size >= need_basic && (n & 255) == 0) {
        unsigned short* W = (unsigned short*)d_ws;
        unsigned* enc = (unsigned*)(W + OFF_ENC);
        int use_bf16 = (ws_size >= need_full) ? 1 : 0;
        unsigned* tbl_bf = (unsigned*)(W + OFF_ENC + (size_t)n * 32);

        ngp_prep_weights<<<40, 256, 0, stream>>>(wb1, wb2, wh1, wh2, wh3, W);
        if (use_bf16) {
            int conv_blocks = (int)((size_t)NLEV * TSZ / 256);
            ngp_conv_table<<<conv_blocks, 256, 0, stream>>>((const float2*)table, tbl_bf);
        }
        int bpl = n >> 8;
        ngp_encode_lm_kernel<<<NLEV * bpl, 256, 0, stream>>>(
            pos, aabb, (const float2*)table, tbl_bf, use_bf16, enc, n);
        ngp_mlp_mfma_kernel<<<n / 256, 256, 0, stream>>>(W, dirs, out, n);
    } else {
        LevelParams lp;
        lp.hashed_mask = 0;
        double pls = exp((log(4096.0) - log(16.0)) / 15.0);
        for (int l = 0; l < NLEV; ++l) {
            double scale = 16.0 * pow(pls, (double)l) - 1.0;
            unsigned res = (unsigned)ceil(scale) + 1u;
            lp.scale[l] = (float)scale;
            lp.res[l] = res;
            if ((unsigned long long)res*(unsigned long long)res*(unsigned long long)res
                > (unsigned long long)TSZ)
                lp.hashed_mask |= (1u << l);
        }
        int block = 256;
        int grid = (n + block - 1) / block;
        ngp_fused_kernel<<<grid, block, 0, stream>>>(pos, dirs, aabb, table,
            wb1, wb2, wh1, wh2, wh3, out, n, lp);
    }
}

// Round 8
// 576.010 us; speedup vs baseline: 15.5566x; 1.0129x over previous
//
#include <hip/hip_runtime.h>
#include <math.h>

namespace {
constexpr int NLEV = 16;
constexpr unsigned TSZ = 1u << 19;
constexpr int HID = 64;

// ws layout (ushort elements):
//   [0,16384)            weights (see below)
//   [16384, 16384+n*32)  enc bf16, layout [16 levels][n] dwords
//   [16384+n*32, ...)    bf16-packed table [16][TSZ] dwords (optional)
constexpr int OFF_WT1  = 0;
constexpr int OFF_WT2  = 2048;
constexpr int OFF_WTH1 = 3072;
constexpr int OFF_WTH2 = 5120;
constexpr int OFF_WTH3 = 9216;
constexpr int OFF_ENC  = 16384;

struct LevelParams {
    float scale[NLEV];
    unsigned res[NLEV];
    unsigned hashed_mask;
};

typedef short bf16x8 __attribute__((ext_vector_type(8)));
typedef float f32x4 __attribute__((ext_vector_type(4)));
} // namespace

__device__ inline unsigned short f2bf(float f) {
    union { float f; unsigned u; } v; v.f = f;
    unsigned r = v.u + 0x7fffu + ((v.u >> 16) & 1u);
    return (unsigned short)(r >> 16);
}
__device__ inline float bf2f(unsigned hi16) {
    union { unsigned u; float f; } v; v.u = hi16 << 16;
    return v.f;
}
__device__ inline unsigned packrelu2(float a, float b) {
    a = fmaxf(a, 0.f); b = fmaxf(b, 0.f);
    return (unsigned)f2bf(a) | ((unsigned)f2bf(b) << 16);
}

// ---------------------------------------------------------------
// Weight prep: transpose + bf16-convert all MLP weights into ws.
// ---------------------------------------------------------------
__global__ void ngp_prep_weights(
    const float* __restrict__ wb1, const float* __restrict__ wb2,
    const float* __restrict__ wh1, const float* __restrict__ wh2,
    const float* __restrict__ wh3, unsigned short* __restrict__ W)
{
    int i = blockIdx.x * 256 + threadIdx.x;
    if (i >= 10240) return;
    float v; int o = i;
    if (o < 2048) {                      // WT1 [64][32]: wb1[k*64+m]
        int m = o >> 5, k = o & 31;
        v = wb1[k * 64 + m];
    } else if ((o -= 2048) < 1024) {     // WT2 [16][64]: wb2[k*16+m]
        int m = o >> 6, k = o & 63;
        v = wb2[k * 16 + m];
    } else if ((o -= 1024) < 2048) {     // WTh1 [64][32]: wh1[k*64+m], k<31
        int m = o >> 5, k = o & 31;
        v = (k < 31) ? wh1[k * 64 + m] : 0.f;
    } else if ((o -= 2048) < 4096) {     // WTh2 [64][64]: wh2[k*64+m]
        int m = o >> 6, k = o & 63;
        v = wh2[k * 64 + m];
    } else {                             // WTh3 [16][64]: wh3[k*3+m], m<3
        o -= 4096;
        int m = o >> 6, k = o & 63;
        v = (m < 3) ? wh3[k * 3 + m] : 0.f;
    }
    W[i] = f2bf(v);
}

// ---------------------------------------------------------------
// Table conversion: f32 float2 -> packed bf16x2 (one dword/entry).
// ---------------------------------------------------------------
__global__ __launch_bounds__(256) void ngp_conv_table(
    const float2* __restrict__ table, unsigned* __restrict__ tbl_bf)
{
    size_t i = (size_t)blockIdx.x * 256 + threadIdx.x;
    float2 f = table[i];
    tbl_bf[i] = (unsigned)f2bf(f.x) | ((unsigned)f2bf(f.y) << 16);
}

// ---------------------------------------------------------------
// Pass 1 v3: level-major encode, 2 points/thread, x-pair merged
// loads. Dense: idx1 = idx0+1. Hashed: idx1 = idx0^1 iff ux even.
// Either way the aligned pair {idx0&~1, idx0|1} is one 8-B load;
// the partner entry needs a separate (exec-masked) load only for
// the non-pairable lanes. Avg 6 tx per point-level instead of 8.
// enc layout: [level][point] dwords (coalesced writes).
// ---------------------------------------------------------------
__global__ __launch_bounds__(256) void ngp_encode_lm2_kernel(
    const float* __restrict__ pos,
    const float* __restrict__ aabb,
    const float2* __restrict__ tbl_f32,
    const unsigned* __restrict__ tbl_bf,
    int use_bf16,
    unsigned* __restrict__ enc_u32,   // [16][n] dwords
    int n)
{
    int bpl = n >> 9;                  // blocks per level (512 pts/block)
    int l = blockIdx.x / bpl;
    int pb = (blockIdx.x - l * bpl) * 512 + threadIdx.x;

    float mn0 = aabb[0], mn1 = aabb[1], mn2 = aabb[2];
    float mx0 = aabb[3], mx1 = aabb[4], mx2 = aabb[5];

    // scale = 16 * (2^(8/15))^l - 1 = 2^(4 + 8l/15) - 1
    float s = exp2f(fmaf((float)l, 8.0f / 15.0f, 4.0f)) - 1.0f;
    unsigned res = (unsigned)ceilf(s) + 1u;
    bool hashed = (unsigned long long)res * res * res > (unsigned long long)TSZ;

    #pragma unroll
    for (int q = 0; q < 2; ++q) {
        int p = pb + q * 256;
        float x = (pos[3*p+0] - mn0) / (mx0 - mn0);
        float y = (pos[3*p+1] - mn1) / (mx1 - mn1);
        float z = (pos[3*p+2] - mn2) / (mx2 - mn2);

        float xs = fmaf(x, s, 0.5f);
        float ys = fmaf(y, s, 0.5f);
        float zs = fmaf(z, s, 0.5f);
        float fx = floorf(xs), fy = floorf(ys), fz = floorf(zs);
        float wx = xs - fx, wy = ys - fy, wz = zs - fz;
        unsigned ux = (unsigned)fx, uy = (unsigned)fy, uz = (unsigned)fz;

        float wyv0 = 1.f - wy, wzv0 = 1.f - wz;
        float a0 = 0.f, a1 = 0.f;

        if (use_bf16) {
            const unsigned* tl = tbl_bf + (size_t)l * TSZ;
            #pragma unroll
            for (int j = 0; j < 4; ++j) {
                unsigned cy = uy + (j & 1);
                unsigned cz = uz + (j >> 1);
                unsigned idx0, idx1;
                if (hashed) {
                    unsigned h = (cy * 2654435761u) ^ (cz * 805459861u);
                    idx0 = (ux ^ h) & (TSZ - 1u);
                    idx1 = ((ux + 1u) ^ h) & (TSZ - 1u);
                } else {
                    idx0 = ux + cy * res + cz * res * res;
                    idx1 = idx0 + 1u;
                }
                bool have1 = hashed ? ((ux & 1u) == 0u) : ((idx0 & 1u) == 0u);
                unsigned base = idx0 & ~1u;
                uint2 pa = *(const uint2*)(tl + base);
                unsigned e0 = (idx0 & 1u) ? pa.y : pa.x;
                unsigned e1 = (idx0 & 1u) ? pa.x : pa.y;
                if (!have1) e1 = tl[idx1];

                float cwyz = ((j & 1) ? wy : wyv0) * ((j >> 1) ? wz : wzv0);
                float cw0 = (1.f - wx) * cwyz;
                float cw1 = wx * cwyz;
                a0 = fmaf(bf2f(e0 & 0xffffu), cw0, a0);
                a1 = fmaf(bf2f(e0 >> 16),    cw0, a1);
                a0 = fmaf(bf2f(e1 & 0xffffu), cw1, a0);
                a1 = fmaf(bf2f(e1 >> 16),    cw1, a1);
            }
        } else {
            const float2* tl = tbl_f32 + (size_t)l * TSZ;
            #pragma unroll
            for (int j = 0; j < 4; ++j) {
                unsigned cy = uy + (j & 1);
                unsigned cz = uz + (j >> 1);
                unsigned idx0, idx1;
                if (hashed) {
                    unsigned h = (cy * 2654435761u) ^ (cz * 805459861u);
                    idx0 = (ux ^ h) & (TSZ - 1u);
                    idx1 = ((ux + 1u) ^ h) & (TSZ - 1u);
                } else {
                    idx0 = ux + cy * res + cz * res * res;
                    idx1 = idx0 + 1u;
                }
                bool have1 = hashed ? ((ux & 1u) == 0u) : ((idx0 & 1u) == 0u);
                unsigned base = idx0 & ~1u;
                float4 pa = *(const float4*)(tl + base);   // 16-B aligned
                float e0x = (idx0 & 1u) ? pa.z : pa.x;
                float e0y = (idx0 & 1u) ? pa.w : pa.y;
                float e1x = (idx0 & 1u) ? pa.x : pa.z;
                float e1y = (idx0 & 1u) ? pa.y : pa.w;
                if (!have1) { float2 t = tl[idx1]; e1x = t.x; e1y = t.y; }

                float cwyz = ((j & 1) ? wy : wyv0) * ((j >> 1) ? wz : wzv0);
                float cw0 = (1.f - wx) * cwyz;
                float cw1 = wx * cwyz;
                a0 = fmaf(e0x, cw0, a0);
                a1 = fmaf(e0y, cw0, a1);
                a0 = fmaf(e1x, cw1, a0);
                a1 = fmaf(e1y, cw1, a1);
            }
        }
        enc_u32[(size_t)l * n + p] = (unsigned)f2bf(a0) | ((unsigned)f2bf(a1) << 16);
    }
}

// ---------------------------------------------------------------
// Pass 2: MFMA MLPs. 4 waves/block, each wave owns 64 points.
// enc is [level][point] dwords -> B-frag = 4 coalesced dword loads.
// Frag mapping (16x16x32 bf16, m89/m97-verified):
//   A: lane = m + 16*kb  holds A[m][kb*8+j]
//   B: lane = n + 16*kb  holds B[kb*8+j][n]
//   C: col = lane&15, row = (lane>>4)*4 + reg
// ---------------------------------------------------------------
__global__ __launch_bounds__(256) void ngp_mlp_mfma_kernel(
    const unsigned short* __restrict__ W,
    const float* __restrict__ dirs,
    float* __restrict__ out,
    int n)
{
    const unsigned short* WT1  = W + OFF_WT1;
    const unsigned short* WT2  = W + OFF_WT2;
    const unsigned short* WTh1 = W + OFF_WTH1;
    const unsigned short* WTh2 = W + OFF_WTH2;
    const unsigned short* WTh3 = W + OFF_WTH3;
    const unsigned* encb = (const unsigned*)(W + OFF_ENC);

    __shared__ unsigned short Hbuf[4][64 * 72];   // [pt][64+pad] bf16
    __shared__ unsigned short HHbuf[4][64 * 40];  // [pt][32+pad] bf16

    const int wv = threadIdx.x >> 6;
    const int lane = threadIdx.x & 63;
    const int cc = lane & 15;
    const int kb = lane >> 4;
    const int ptbase = (blockIdx.x * 4 + wv) * 64;

    unsigned short* Hs = Hbuf[wv];
    unsigned short* HH = HHbuf[wv];

    const f32x4 zero4 = {0.f, 0.f, 0.f, 0.f};

    // ===== GEMM1: h = relu(WT1[64x32] @ enc[32x64]) =====
    bf16x8 Be[4], A1[4];
    #pragma unroll
    for (int nt = 0; nt < 4; ++nt) {
        union { unsigned u[4]; bf16x8 v; } uu;
        int p = ptbase + nt*16 + cc;
        #pragma unroll
        for (int q = 0; q < 4; ++q)
            uu.u[q] = encb[(size_t)(kb*4 + q) * n + p];
        Be[nt] = uu.v;
    }
    #pragma unroll
    for (int mt = 0; mt < 4; ++mt)
        A1[mt] = *(const bf16x8*)(WT1 + (mt*16 + cc)*32 + kb*8);
    f32x4 acc[4][4];
    #pragma unroll
    for (int mt = 0; mt < 4; ++mt)
        #pragma unroll
        for (int nt = 0; nt < 4; ++nt)
            acc[mt][nt] = __builtin_amdgcn_mfma_f32_16x16x32_bf16(A1[mt], Be[nt], zero4, 0, 0, 0);
    #pragma unroll
    for (int mt = 0; mt < 4; ++mt)
        #pragma unroll
        for (int nt = 0; nt < 4; ++nt) {
            int pt = nt*16 + cc, hid = mt*16 + kb*4;
            *(uint2*)(Hs + pt*72 + hid) =
                make_uint2(packrelu2(acc[mt][nt][0], acc[mt][nt][1]),
                           packrelu2(acc[mt][nt][2], acc[mt][nt][3]));
        }

    // ===== GEMM2: bo = WT2[16x64] @ h[64x64]  (no activation) =====
    bf16x8 A2[2];
    #pragma unroll
    for (int ks = 0; ks < 2; ++ks)
        A2[ks] = *(const bf16x8*)(WT2 + cc*64 + ks*32 + kb*8);
    f32x4 acc2[4];
    #pragma unroll
    for (int nt = 0; nt < 4; ++nt) {
        bf16x8 b0 = *(const bf16x8*)(Hs + (nt*16 + cc)*72 +  0 + kb*8);
        bf16x8 b1 = *(const bf16x8*)(Hs + (nt*16 + cc)*72 + 32 + kb*8);
        acc2[nt] = __builtin_amdgcn_mfma_f32_16x16x32_bf16(A2[0], b0, zero4, 0, 0, 0);
        acc2[nt] = __builtin_amdgcn_mfma_f32_16x16x32_bf16(A2[1], b1, acc2[nt], 0, 0, 0);
    }

    // ===== SH encode (lane <-> point) into HH[pt][0..15] =====
    {
        int p = ptbase + lane;
        float t0 = (dirs[3*p+0] + 1.f) * 0.5f;
        float t1 = (dirs[3*p+1] + 1.f) * 0.5f;
        float t2 = (dirs[3*p+2] + 1.f) * 0.5f;
        float dx = t0*2.f - 1.f, dy = t1*2.f - 1.f, dz = t2*2.f - 1.f;
        float x2 = dx*dx, y2 = dy*dy, z2 = dz*dz;
        float xy = dx*dy, xz = dx*dz, yz = dy*dz;
        float sh[16];
        sh[0]  = 0.28209479177387814f;
        sh[1]  = -0.48860251190291987f * dy;
        sh[2]  = 0.48860251190291987f * dz;
        sh[3]  = -0.48860251190291987f * dx;
        sh[4]  = 1.0925484305920792f * xy;
        sh[5]  = -1.0925484305920792f * yz;
        sh[6]  = 0.94617469575756f * z2 - 0.31539156525252f;
        sh[7]  = -1.0925484305920792f * xz;
        sh[8]  = 0.5462742152960396f * x2 - 0.5462742152960396f * y2;
        sh[9]  = 0.5900435899266435f * dy * (-3.f*x2 + y2);
        sh[10] = 2.890611442640554f * xy * dz;
        sh[11] = 0.4570457994644657f * dy * (1.f - 5.f*z2);
        sh[12] = 0.3731763325901154f * dz * (5.f*z2 - 3.f);
        sh[13] = 0.4570457994644657f * dx * (1.f - 5.f*z2);
        sh[14] = 1.445305721320277f * dz * (x2 - y2);
        sh[15] = 0.5900435899266435f * dx * (x2 - 3.f*y2);
        unsigned u[8];
        #pragma unroll
        for (int j = 0; j < 8; ++j)
            u[j] = (unsigned)f2bf(sh[2*j]) | ((unsigned)f2bf(sh[2*j+1]) << 16);
        *(uint4*)(HH + lane*40)     = make_uint4(u[0], u[1], u[2], u[3]);
        *(uint4*)(HH + lane*40 + 8) = make_uint4(u[4], u[5], u[6], u[7]);
    }

    // geo -> HH[pt][16..30]; row 0 (density) parked in dead slot 31
    // (WTh1 row k=31 is zeroed, so hh[31] never contributes).
    #pragma unroll
    for (int nt = 0; nt < 4; ++nt) {
        int pt = nt*16 + cc;
        #pragma unroll
        for (int r = 0; r < 4; ++r) {
            int row = kb*4 + r;
            int slot = (row == 0) ? 31 : (15 + row);
            HH[pt*40 + slot] = f2bf(acc2[nt][r]);
        }
        if (kb == 0)
            out[(size_t)3*n + ptbase + pt] = expf(acc2[nt][0] - 1.0f);
    }

    // ===== GEMM3: h1 = relu(WTh1[64x32] @ hh[32x64]) =====
    bf16x8 A3[4], Bh[4];
    #pragma unroll
    for (int mt = 0; mt < 4; ++mt)
        A3[mt] = *(const bf16x8*)(WTh1 + (mt*16 + cc)*32 + kb*8);
    #pragma unroll
    for (int nt = 0; nt < 4; ++nt)
        Bh[nt] = *(const bf16x8*)(HH + (nt*16 + cc)*40 + kb*8);
    #pragma unroll
    for (int mt = 0; mt < 4; ++mt)
        #pragma unroll
        for (int nt = 0; nt < 4; ++nt)
            acc[mt][nt] = __builtin_amdgcn_mfma_f32_16x16x32_bf16(A3[mt], Bh[nt], zero4, 0, 0, 0);
    #pragma unroll
    for (int mt = 0; mt < 4; ++mt)
        #pragma unroll
        for (int nt = 0; nt < 4; ++nt) {
            int pt = nt*16 + cc, hid = mt*16 + kb*4;
            *(uint2*)(Hs + pt*72 + hid) =
                make_uint2(packrelu2(acc[mt][nt][0], acc[mt][nt][1]),
                           packrelu2(acc[mt][nt][2], acc[mt][nt][3]));
        }

    // ===== GEMM4: h2 = relu(WTh2[64x64] @ h1[64x64]) =====
    bf16x8 A4[4][2], B4[4][2];
    #pragma unroll
    for (int mt = 0; mt < 4; ++mt)
        #pragma unroll
        for (int ks = 0; ks < 2; ++ks)
            A4[mt][ks] = *(const bf16x8*)(WTh2 + (mt*16 + cc)*64 + ks*32 + kb*8);
    #pragma unroll
    for (int nt = 0; nt < 4; ++nt)
        #pragma unroll
        for (int ks = 0; ks < 2; ++ks)
            B4[nt][ks] = *(const bf16x8*)(Hs + (nt*16 + cc)*72 + ks*32 + kb*8);
    #pragma unroll
    for (int mt = 0; mt < 4; ++mt)
        #pragma unroll
        for (int nt = 0; nt < 4; ++nt) {
            acc[mt][nt] = __builtin_amdgcn_mfma_f32_16x16x32_bf16(A4[mt][0], B4[nt][0], zero4, 0, 0, 0);
            acc[mt][nt] = __builtin_amdgcn_mfma_f32_16x16x32_bf16(A4[mt][1], B4[nt][1], acc[mt][nt], 0, 0, 0);
        }
    #pragma unroll
    for (int mt = 0; mt < 4; ++mt)
        #pragma unroll
        for (int nt = 0; nt < 4; ++nt) {
            int pt = nt*16 + cc, hid = mt*16 + kb*4;
            *(uint2*)(Hs + pt*72 + hid) =
                make_uint2(packrelu2(acc[mt][nt][0], acc[mt][nt][1]),
                           packrelu2(acc[mt][nt][2], acc[mt][nt][3]));
        }

    // ===== GEMM5: rgb = sigmoid(WTh3[16x64] @ h2[64x64]), rows 0..2 =====
    bf16x8 A5[2];
    #pragma unroll
    for (int ks = 0; ks < 2; ++ks)
        A5[ks] = *(const bf16x8*)(WTh3 + cc*64 + ks*32 + kb*8);
    #pragma unroll
    for (int nt = 0; nt < 4; ++nt) {
        bf16x8 b0 = *(const bf16x8*)(Hs + (nt*16 + cc)*72 +  0 + kb*8);
        bf16x8 b1 = *(const bf16x8*)(Hs + (nt*16 + cc)*72 + 32 + kb*8);
        f32x4 a3 = __builtin_amdgcn_mfma_f32_16x16x32_bf16(A5[0], b0, zero4, 0, 0, 0);
        a3 = __builtin_amdgcn_mfma_f32_16x16x32_bf16(A5[1], b1, a3, 0, 0, 0);
        if (kb == 0) {
            size_t p = (size_t)(ptbase + nt*16 + cc);
            out[3*p + 0] = 1.f / (1.f + expf(-a3[0]));
            out[3*p + 1] = 1.f / (1.f + expf(-a3[1]));
            out[3*p + 2] = 1.f / (1.f + expf(-a3[2]));
        }
    }
}

// ---------------------------------------------------------------
// Fallback: proven fused scalar kernel (ws too small / odd n).
// ---------------------------------------------------------------
__global__ __launch_bounds__(256) void ngp_fused_kernel(
    const float* __restrict__ pos,
    const float* __restrict__ dirs,
    const float* __restrict__ aabb,
    const float* __restrict__ table,
    const float* __restrict__ wb1,
    const float* __restrict__ wb2,
    const float* __restrict__ wh1,
    const float* __restrict__ wh2,
    const float* __restrict__ wh3,
    float* __restrict__ out,
    int n, LevelParams lp)
{
    int i = blockIdx.x * blockDim.x + threadIdx.x;
    if (i >= n) return;

    float px = pos[3*i+0], py = pos[3*i+1], pz = pos[3*i+2];
    float mn0 = aabb[0], mn1 = aabb[1], mn2 = aabb[2];
    float mx0 = aabb[3], mx1 = aabb[4], mx2 = aabb[5];
    float x = (px - mn0) / (mx0 - mn0);
    float y = (py - mn1) / (mx1 - mn1);
    float z = (pz - mn2) / (mx2 - mn2);

    float enc[2*NLEV];
    #pragma unroll
    for (int l = 0; l < NLEV; ++l) {
        float s = lp.scale[l];
        unsigned res = lp.res[l];
        bool hashed = (lp.hashed_mask >> l) & 1u;
        float xs = fmaf(x, s, 0.5f);
        float ys = fmaf(y, s, 0.5f);
        float zs = fmaf(z, s, 0.5f);
        float fx = floorf(xs), fy = floorf(ys), fz = floorf(zs);
        float wx = xs - fx, wy = ys - fy, wz = zs - fz;
        unsigned ux = (unsigned)fx, uy = (unsigned)fy, uz = (unsigned)fz;
        const float2* tl = (const float2*)table + (size_t)l * TSZ;
        float a0 = 0.f, a1 = 0.f;
        #pragma unroll
        for (int c = 0; c < 8; ++c) {
            unsigned cx = ux + (c & 1);
            unsigned cy = uy + ((c >> 1) & 1);
            unsigned cz = uz + ((c >> 2) & 1);
            unsigned idx;
            if (hashed)
                idx = (cx ^ (cy * 2654435761u) ^ (cz * 805459861u)) & (TSZ - 1u);
            else
                idx = cx + cy * res + cz * res * res;
            float cw = ((c & 1) ? wx : 1.f - wx)
                     * (((c >> 1) & 1) ? wy : 1.f - wy)
                     * (((c >> 2) & 1) ? wz : 1.f - wz);
            float2 f = tl[idx];
            a0 = fmaf(f.x, cw, a0);
            a1 = fmaf(f.y, cw, a1);
        }
        enc[2*l]   = a0;
        enc[2*l+1] = a1;
    }

    float h[HID];
    #pragma unroll
    for (int j = 0; j < HID; ++j) h[j] = 0.f;
    #pragma unroll
    for (int k = 0; k < 2*NLEV; ++k) {
        float e = enc[k];
        #pragma unroll
        for (int j = 0; j < HID; ++j)
            h[j] = fmaf(e, wb1[k*HID+j], h[j]);
    }
    #pragma unroll
    for (int j = 0; j < HID; ++j) h[j] = fmaxf(h[j], 0.f);

    float bo[16];
    #pragma unroll
    for (int j = 0; j < 16; ++j) bo[j] = 0.f;
    #pragma unroll
    for (int k = 0; k < HID; ++k) {
        float e = h[k];
        #pragma unroll
        for (int j = 0; j < 16; ++j)
            bo[j] = fmaf(e, wb2[k*16+j], bo[j]);
    }
    float density = expf(bo[0] - 1.0f);

    float t0 = (dirs[3*i+0] + 1.f) * 0.5f;
    float t1 = (dirs[3*i+1] + 1.f) * 0.5f;
    float t2 = (dirs[3*i+2] + 1.f) * 0.5f;
    float dx = t0*2.f - 1.f, dy = t1*2.f - 1.f, dz = t2*2.f - 1.f;
    float x2 = dx*dx, y2 = dy*dy, z2 = dz*dz;
    float xy = dx*dy, xz = dx*dz, yz = dy*dz;
    float hh[31];
    hh[0]  = 0.28209479177387814f;
    hh[1]  = -0.48860251190291987f * dy;
    hh[2]  = 0.48860251190291987f * dz;
    hh[3]  = -0.48860251190291987f * dx;
    hh[4]  = 1.0925484305920792f * xy;
    hh[5]  = -1.0925484305920792f * yz;
    hh[6]  = 0.94617469575756f * z2 - 0.31539156525252f;
    hh[7]  = -1.0925484305920792f * xz;
    hh[8]  = 0.5462742152960396f * x2 - 0.5462742152960396f * y2;
    hh[9]  = 0.5900435899266435f * dy * (-3.f*x2 + y2);
    hh[10] = 2.890611442640554f * xy * dz;
    hh[11] = 0.4570457994644657f * dy * (1.f - 5.f*z2);
    hh[12] = 0.3731763325901154f * dz * (5.f*z2 - 3.f);
    hh[13] = 0.4570457994644657f * dx * (1.f - 5.f*z2);
    hh[14] = 1.445305721320277f * dz * (x2 - y2);
    hh[15] = 0.5900435899266435f * dx * (x2 - 3.f*y2);
    #pragma unroll
    for (int j = 0; j < 15; ++j) hh[16+j] = bo[1+j];

    float h1[HID];
    #pragma unroll
    for (int j = 0; j < HID; ++j) h1[j] = 0.f;
    #pragma unroll
    for (int k = 0; k < 31; ++k) {
        float e = hh[k];
        #pragma unroll
        for (int j = 0; j < HID; ++j)
            h1[j] = fmaf(e, wh1[k*HID+j], h1[j]);
    }
    #pragma unroll
    for (int j = 0; j < HID; ++j) h1[j] = fmaxf(h1[j], 0.f);

    float h2[HID];
    #pragma unroll
    for (int j = 0; j < HID; ++j) h2[j] = 0.f;
    #pragma unroll
    for (int k = 0; k < HID; ++k) {
        float e = h1[k];
        #pragma unroll
        for (int j = 0; j < HID; ++j)
            h2[j] = fmaf(e, wh2[k*HID+j], h2[j]);
    }
    #pragma unroll
    for (int j = 0; j < HID; ++j) h2[j] = fmaxf(h2[j], 0.f);

    float r0 = 0.f, r1 = 0.f, r2 = 0.f;
    #pragma unroll
    for (int k = 0; k < HID; ++k) {
        float e = h2[k];
        r0 = fmaf(e, wh3[k*3+0], r0);
        r1 = fmaf(e, wh3[k*3+1], r1);
        r2 = fmaf(e, wh3[k*3+2], r2);
    }
    r0 = 1.f / (1.f + expf(-r0));
    r1 = 1.f / (1.f + expf(-r1));
    r2 = 1.f / (1.f + expf(-r2));

    out[3*i+0] = r0;
    out[3*i+1] = r1;
    out[3*i+2] = r2;
    out[(size_t)3*n + i] = density;
}

extern "C" void kernel_launch(void* const* d_in, const int* in_sizes, int n_in,
                              void* d_out, int out_size, void* d_ws, size_t ws_size,
                              hipStream_t stream) {
    const float* pos   = (const float*)d_in[0];
    const float* dirs  = (const float*)d_in[1];
    const float* aabb  = (const float*)d_in[2];
    const float* table = (const float*)d_in[3];
    const float* wb1   = (const float*)d_in[4];
    const float* wb2   = (const float*)d_in[5];
    const float* wh1   = (const float*)d_in[6];
    const float* wh2   = (const float*)d_in[7];
    const float* wh3   = (const float*)d_in[8];
    float* out = (float*)d_out;
    int n = in_sizes[0] / 3;

    size_t need_basic = 32768 + (size_t)n * 64;                      // weights + enc
    size_t need_full  = need_basic + (size_t)NLEV * TSZ * 4;         // + bf16 table
    if (ws_size >= need_basic && (n & 511) == 0) {
        unsigned short* W = (unsigned short*)d_ws;
        unsigned* enc = (unsigned*)(W + OFF_ENC);
        int use_bf16 = (ws_size >= need_full) ? 1 : 0;
        unsigned* tbl_bf = (unsigned*)(W + OFF_ENC + (size_t)n * 32);

        ngp_prep_weights<<<40, 256, 0, stream>>>(wb1, wb2, wh1, wh2, wh3, W);
        if (use_bf16) {
            int conv_blocks = (int)((size_t)NLEV * TSZ / 256);
            ngp_conv_table<<<conv_blocks, 256, 0, stream>>>((const float2*)table, tbl_bf);
        }
        int bpl = n >> 9;
        ngp_encode_lm2_kernel<<<NLEV * bpl, 256, 0, stream>>>(
            pos, aabb, (const float2*)table, tbl_bf, use_bf16, enc, n);
        ngp_mlp_mfma_kernel<<<n / 256, 256, 0, stream>>>(W, dirs, out, n);
    } else {
        LevelParams lp;
        lp.hashed_mask = 0;
        double pls = exp((log(4096.0) - log(16.0)) / 15.0);
        for (int l = 0; l < NLEV; ++l) {
            double scale = 16.0 * pow(pls, (double)l) - 1.0;
            unsigned res = (unsigned)ceil(scale) + 1u;
            lp.scale[l] = (float)scale;
            lp.res[l] = res;
            if ((unsigned long long)res*(unsigned long long)res*(unsigned long long)res
                > (unsigned long long)TSZ)
                lp.hashed_mask |= (1u << l);
        }
        int block = 256;
        int grid = (n + block - 1) / block;
        ngp_fused_kernel<<<grid, block, 0, stream>>>(pos, dirs, aabb, table,
            wb1, wb2, wh1, wh2, wh3, out, n, lp);
    }
}

// Round 9
// 547.250 us; speedup vs baseline: 16.3742x; 1.0526x over previous
//
#include <hip/hip_runtime.h>
#include <math.h>

namespace {
constexpr int NLEV = 16;
constexpr unsigned TSZ = 1u << 19;
constexpr int HID = 64;

// ws layout (ushort elements):
//   [0,16384)            weights (see below)
//   [16384, 16384+n*32)  enc bf16, layout [16 levels][n] dwords
//   [16384+n*32, ...)    bf16-packed table [16][TSZ] dwords (optional)
constexpr int OFF_WT1  = 0;
constexpr int OFF_WT2  = 2048;
constexpr int OFF_WTH1 = 3072;
constexpr int OFF_WTH2 = 5120;
constexpr int OFF_WTH3 = 9216;
constexpr int OFF_ENC  = 16384;

struct LevelParams {
    float scale[NLEV];
    unsigned res[NLEV];
    unsigned hashed_mask;
};

typedef short bf16x8 __attribute__((ext_vector_type(8)));
typedef float f32x4 __attribute__((ext_vector_type(4)));
} // namespace

__device__ inline unsigned short f2bf(float f) {
    union { float f; unsigned u; } v; v.f = f;
    unsigned r = v.u + 0x7fffu + ((v.u >> 16) & 1u);
    return (unsigned short)(r >> 16);
}
__device__ inline float bf2f(unsigned hi16) {
    union { unsigned u; float f; } v; v.u = hi16 << 16;
    return v.f;
}
__device__ inline unsigned packrelu2(float a, float b) {
    a = fmaxf(a, 0.f); b = fmaxf(b, 0.f);
    return (unsigned)f2bf(a) | ((unsigned)f2bf(b) << 16);
}

// ---------------------------------------------------------------
// Weight prep: transpose + bf16-convert all MLP weights into ws.
// ---------------------------------------------------------------
__global__ void ngp_prep_weights(
    const float* __restrict__ wb1, const float* __restrict__ wb2,
    const float* __restrict__ wh1, const float* __restrict__ wh2,
    const float* __restrict__ wh3, unsigned short* __restrict__ W)
{
    int i = blockIdx.x * 256 + threadIdx.x;
    if (i >= 10240) return;
    float v; int o = i;
    if (o < 2048) {                      // WT1 [64][32]: wb1[k*64+m]
        int m = o >> 5, k = o & 31;
        v = wb1[k * 64 + m];
    } else if ((o -= 2048) < 1024) {     // WT2 [16][64]: wb2[k*16+m]
        int m = o >> 6, k = o & 63;
        v = wb2[k * 16 + m];
    } else if ((o -= 1024) < 2048) {     // WTh1 [64][32]: wh1[k*64+m], k<31
        int m = o >> 5, k = o & 31;
        v = (k < 31) ? wh1[k * 64 + m] : 0.f;
    } else if ((o -= 2048) < 4096) {     // WTh2 [64][64]: wh2[k*64+m]
        int m = o >> 6, k = o & 63;
        v = wh2[k * 64 + m];
    } else {                             // WTh3 [16][64]: wh3[k*3+m], m<3
        o -= 4096;
        int m = o >> 6, k = o & 63;
        v = (m < 3) ? wh3[k * 3 + m] : 0.f;
    }
    W[i] = f2bf(v);
}

// ---------------------------------------------------------------
// Table conversion: f32 float2 -> packed bf16x2 (one dword/entry).
// ---------------------------------------------------------------
__global__ __launch_bounds__(256) void ngp_conv_table(
    const float2* __restrict__ table, unsigned* __restrict__ tbl_bf)
{
    size_t i = (size_t)blockIdx.x * 256 + threadIdx.x;
    float2 f = table[i];
    tbl_bf[i] = (unsigned)f2bf(f.x) | ((unsigned)f2bf(f.y) << 16);
}

// ---------------------------------------------------------------
// Pass 1 v4: level-major encode, 2 points/thread, BATCHED loads.
// All 16 gathers (8 per point) are issued before any consumption:
// addr(p0) -> load(p0) -> addr(p1) -> load(p1) -> fma/store(p0)
// -> fma/store(p1). Forces ~16 outstanding gathers per thread to
// hide L2/L3 latency (the R7/R8 kernels at VGPR 24-28 serialized
// on vmcnt). enc layout: [level][point] dwords.
// ---------------------------------------------------------------
__global__ __launch_bounds__(256) void ngp_encode_lm3_kernel(
    const float* __restrict__ pos,
    const float* __restrict__ aabb,
    const float2* __restrict__ tbl_f32,
    const unsigned* __restrict__ tbl_bf,
    int use_bf16,
    unsigned* __restrict__ enc_u32,   // [16][n] dwords
    int n)
{
    int bpl = n >> 9;                  // blocks per level (512 pts/block)
    int l = blockIdx.x / bpl;
    int pb = (blockIdx.x - l * bpl) * 512 + threadIdx.x;

    float mn0 = aabb[0], mn1 = aabb[1], mn2 = aabb[2];
    float mx0 = aabb[3], mx1 = aabb[4], mx2 = aabb[5];

    // scale = 16 * (2^(8/15))^l - 1 = 2^(4 + 8l/15) - 1
    float s = exp2f(fmaf((float)l, 8.0f / 15.0f, 4.0f)) - 1.0f;
    unsigned res = (unsigned)ceilf(s) + 1u;
    bool hashed = (unsigned long long)res * res * res > (unsigned long long)TSZ;

    unsigned idx[2][8];
    float cw[2][8];

    // ---- phase A: addresses + weights for both points ----
    #pragma unroll
    for (int q = 0; q < 2; ++q) {
        int p = pb + q * 256;
        float x = (pos[3*p+0] - mn0) / (mx0 - mn0);
        float y = (pos[3*p+1] - mn1) / (mx1 - mn1);
        float z = (pos[3*p+2] - mn2) / (mx2 - mn2);

        float xs = fmaf(x, s, 0.5f);
        float ys = fmaf(y, s, 0.5f);
        float zs = fmaf(z, s, 0.5f);
        float fx = floorf(xs), fy = floorf(ys), fz = floorf(zs);
        float wx = xs - fx, wy = ys - fy, wz = zs - fz;
        unsigned ux = (unsigned)fx, uy = (unsigned)fy, uz = (unsigned)fz;
        float wx0 = 1.f - wx, wy0 = 1.f - wy, wz0 = 1.f - wz;

        #pragma unroll
        for (int j = 0; j < 4; ++j) {
            unsigned cy = uy + (j & 1);
            unsigned cz = uz + (j >> 1);
            unsigned i0, i1;
            if (hashed) {
                unsigned h = (cy * 2654435761u) ^ (cz * 805459861u);
                i0 = (ux ^ h) & (TSZ - 1u);
                i1 = ((ux + 1u) ^ h) & (TSZ - 1u);
            } else {
                i0 = ux + cy * res + cz * res * res;
                i1 = i0 + 1u;
            }
            idx[q][2*j]   = i0;
            idx[q][2*j+1] = i1;
            float cwyz = ((j & 1) ? wy : wy0) * ((j >> 1) ? wz : wz0);
            cw[q][2*j]   = wx0 * cwyz;
            cw[q][2*j+1] = wx  * cwyz;
        }
    }

    if (use_bf16) {
        const unsigned* tl = tbl_bf + (size_t)l * TSZ;
        unsigned u[2][8];
        // ---- phase B: issue ALL 16 gathers back-to-back ----
        #pragma unroll
        for (int q = 0; q < 2; ++q)
            #pragma unroll
            for (int c = 0; c < 8; ++c)
                u[q][c] = tl[idx[q][c]];
        // ---- phase C: consume ----
        #pragma unroll
        for (int q = 0; q < 2; ++q) {
            float a0 = 0.f, a1 = 0.f;
            #pragma unroll
            for (int c = 0; c < 8; ++c) {
                a0 = fmaf(bf2f(u[q][c] & 0xffffu), cw[q][c], a0);
                a1 = fmaf(bf2f(u[q][c] >> 16),     cw[q][c], a1);
            }
            enc_u32[(size_t)l * n + pb + q * 256] =
                (unsigned)f2bf(a0) | ((unsigned)f2bf(a1) << 16);
        }
    } else {
        const float2* tl = tbl_f32 + (size_t)l * TSZ;
        float2 u[2][8];
        #pragma unroll
        for (int q = 0; q < 2; ++q)
            #pragma unroll
            for (int c = 0; c < 8; ++c)
                u[q][c] = tl[idx[q][c]];
        #pragma unroll
        for (int q = 0; q < 2; ++q) {
            float a0 = 0.f, a1 = 0.f;
            #pragma unroll
            for (int c = 0; c < 8; ++c) {
                a0 = fmaf(u[q][c].x, cw[q][c], a0);
                a1 = fmaf(u[q][c].y, cw[q][c], a1);
            }
            enc_u32[(size_t)l * n + pb + q * 256] =
                (unsigned)f2bf(a0) | ((unsigned)f2bf(a1) << 16);
        }
    }
}

// ---------------------------------------------------------------
// Pass 2: MFMA MLPs. 4 waves/block, each wave owns 64 points.
// enc is [level][point] dwords -> B-frag = 4 coalesced dword loads.
// Frag mapping (16x16x32 bf16, m89/m97-verified):
//   A: lane = m + 16*kb  holds A[m][kb*8+j]
//   B: lane = n + 16*kb  holds B[kb*8+j][n]
//   C: col = lane&15, row = (lane>>4)*4 + reg
// ---------------------------------------------------------------
__global__ __launch_bounds__(256) void ngp_mlp_mfma_kernel(
    const unsigned short* __restrict__ W,
    const float* __restrict__ dirs,
    float* __restrict__ out,
    int n)
{
    const unsigned short* WT1  = W + OFF_WT1;
    const unsigned short* WT2  = W + OFF_WT2;
    const unsigned short* WTh1 = W + OFF_WTH1;
    const unsigned short* WTh2 = W + OFF_WTH2;
    const unsigned short* WTh3 = W + OFF_WTH3;
    const unsigned* encb = (const unsigned*)(W + OFF_ENC);

    __shared__ unsigned short Hbuf[4][64 * 72];   // [pt][64+pad] bf16
    __shared__ unsigned short HHbuf[4][64 * 40];  // [pt][32+pad] bf16

    const int wv = threadIdx.x >> 6;
    const int lane = threadIdx.x & 63;
    const int cc = lane & 15;
    const int kb = lane >> 4;
    const int ptbase = (blockIdx.x * 4 + wv) * 64;

    unsigned short* Hs = Hbuf[wv];
    unsigned short* HH = HHbuf[wv];

    const f32x4 zero4 = {0.f, 0.f, 0.f, 0.f};

    // ===== GEMM1: h = relu(WT1[64x32] @ enc[32x64]) =====
    bf16x8 Be[4], A1[4];
    #pragma unroll
    for (int nt = 0; nt < 4; ++nt) {
        union { unsigned u[4]; bf16x8 v; } uu;
        int p = ptbase + nt*16 + cc;
        #pragma unroll
        for (int q = 0; q < 4; ++q)
            uu.u[q] = encb[(size_t)(kb*4 + q) * n + p];
        Be[nt] = uu.v;
    }
    #pragma unroll
    for (int mt = 0; mt < 4; ++mt)
        A1[mt] = *(const bf16x8*)(WT1 + (mt*16 + cc)*32 + kb*8);
    f32x4 acc[4][4];
    #pragma unroll
    for (int mt = 0; mt < 4; ++mt)
        #pragma unroll
        for (int nt = 0; nt < 4; ++nt)
            acc[mt][nt] = __builtin_amdgcn_mfma_f32_16x16x32_bf16(A1[mt], Be[nt], zero4, 0, 0, 0);
    #pragma unroll
    for (int mt = 0; mt < 4; ++mt)
        #pragma unroll
        for (int nt = 0; nt < 4; ++nt) {
            int pt = nt*16 + cc, hid = mt*16 + kb*4;
            *(uint2*)(Hs + pt*72 + hid) =
                make_uint2(packrelu2(acc[mt][nt][0], acc[mt][nt][1]),
                           packrelu2(acc[mt][nt][2], acc[mt][nt][3]));
        }

    // ===== GEMM2: bo = WT2[16x64] @ h[64x64]  (no activation) =====
    bf16x8 A2[2];
    #pragma unroll
    for (int ks = 0; ks < 2; ++ks)
        A2[ks] = *(const bf16x8*)(WT2 + cc*64 + ks*32 + kb*8);
    f32x4 acc2[4];
    #pragma unroll
    for (int nt = 0; nt < 4; ++nt) {
        bf16x8 b0 = *(const bf16x8*)(Hs + (nt*16 + cc)*72 +  0 + kb*8);
        bf16x8 b1 = *(const bf16x8*)(Hs + (nt*16 + cc)*72 + 32 + kb*8);
        acc2[nt] = __builtin_amdgcn_mfma_f32_16x16x32_bf16(A2[0], b0, zero4, 0, 0, 0);
        acc2[nt] = __builtin_amdgcn_mfma_f32_16x16x32_bf16(A2[1], b1, acc2[nt], 0, 0, 0);
    }

    // ===== SH encode (lane <-> point) into HH[pt][0..15] =====
    {
        int p = ptbase + lane;
        float t0 = (dirs[3*p+0] + 1.f) * 0.5f;
        float t1 = (dirs[3*p+1] + 1.f) * 0.5f;
        float t2 = (dirs[3*p+2] + 1.f) * 0.5f;
        float dx = t0*2.f - 1.f, dy = t1*2.f - 1.f, dz = t2*2.f - 1.f;
        float x2 = dx*dx, y2 = dy*dy, z2 = dz*dz;
        float xy = dx*dy, xz = dx*dz, yz = dy*dz;
        float sh[16];
        sh[0]  = 0.28209479177387814f;
        sh[1]  = -0.48860251190291987f * dy;
        sh[2]  = 0.48860251190291987f * dz;
        sh[3]  = -0.48860251190291987f * dx;
        sh[4]  = 1.0925484305920792f * xy;
        sh[5]  = -1.0925484305920792f * yz;
        sh[6]  = 0.94617469575756f * z2 - 0.31539156525252f;
        sh[7]  = -1.0925484305920792f * xz;
        sh[8]  = 0.5462742152960396f * x2 - 0.5462742152960396f * y2;
        sh[9]  = 0.5900435899266435f * dy * (-3.f*x2 + y2);
        sh[10] = 2.890611442640554f * xy * dz;
        sh[11] = 0.4570457994644657f * dy * (1.f - 5.f*z2);
        sh[12] = 0.3731763325901154f * dz * (5.f*z2 - 3.f);
        sh[13] = 0.4570457994644657f * dx * (1.f - 5.f*z2);
        sh[14] = 1.445305721320277f * dz * (x2 - y2);
        sh[15] = 0.5900435899266435f * dx * (x2 - 3.f*y2);
        unsigned u[8];
        #pragma unroll
        for (int j = 0; j < 8; ++j)
            u[j] = (unsigned)f2bf(sh[2*j]) | ((unsigned)f2bf(sh[2*j+1]) << 16);
        *(uint4*)(HH + lane*40)     = make_uint4(u[0], u[1], u[2], u[3]);
        *(uint4*)(HH + lane*40 + 8) = make_uint4(u[4], u[5], u[6], u[7]);
    }

    // geo -> HH[pt][16..30]; row 0 (density) parked in dead slot 31
    // (WTh1 row k=31 is zeroed, so hh[31] never contributes).
    #pragma unroll
    for (int nt = 0; nt < 4; ++nt) {
        int pt = nt*16 + cc;
        #pragma unroll
        for (int r = 0; r < 4; ++r) {
            int row = kb*4 + r;
            int slot = (row == 0) ? 31 : (15 + row);
            HH[pt*40 + slot] = f2bf(acc2[nt][r]);
        }
        if (kb == 0)
            out[(size_t)3*n + ptbase + pt] = expf(acc2[nt][0] - 1.0f);
    }

    // ===== GEMM3: h1 = relu(WTh1[64x32] @ hh[32x64]) =====
    bf16x8 A3[4], Bh[4];
    #pragma unroll
    for (int mt = 0; mt < 4; ++mt)
        A3[mt] = *(const bf16x8*)(WTh1 + (mt*16 + cc)*32 + kb*8);
    #pragma unroll
    for (int nt = 0; nt < 4; ++nt)
        Bh[nt] = *(const bf16x8*)(HH + (nt*16 + cc)*40 + kb*8);
    #pragma unroll
    for (int mt = 0; mt < 4; ++mt)
        #pragma unroll
        for (int nt = 0; nt < 4; ++nt)
            acc[mt][nt] = __builtin_amdgcn_mfma_f32_16x16x32_bf16(A3[mt], Bh[nt], zero4, 0, 0, 0);
    #pragma unroll
    for (int mt = 0; mt < 4; ++mt)
        #pragma unroll
        for (int nt = 0; nt < 4; ++nt) {
            int pt = nt*16 + cc, hid = mt*16 + kb*4;
            *(uint2*)(Hs + pt*72 + hid) =
                make_uint2(packrelu2(acc[mt][nt][0], acc[mt][nt][1]),
                           packrelu2(acc[mt][nt][2], acc[mt][nt][3]));
        }

    // ===== GEMM4: h2 = relu(WTh2[64x64] @ h1[64x64]) =====
    bf16x8 A4[4][2], B4[4][2];
    #pragma unroll
    for (int mt = 0; mt < 4; ++mt)
        #pragma unroll
        for (int ks = 0; ks < 2; ++ks)
            A4[mt][ks] = *(const bf16x8*)(WTh2 + (mt*16 + cc)*64 + ks*32 + kb*8);
    #pragma unroll
    for (int nt = 0; nt < 4; ++nt)
        #pragma unroll
        for (int ks = 0; ks < 2; ++ks)
            B4[nt][ks] = *(const bf16x8*)(Hs + (nt*16 + cc)*72 + ks*32 + kb*8);
    #pragma unroll
    for (int mt = 0; mt < 4; ++mt)
        #pragma unroll
        for (int nt = 0; nt < 4; ++nt) {
            acc[mt][nt] = __builtin_amdgcn_mfma_f32_16x16x32_bf16(A4[mt][0], B4[nt][0], zero4, 0, 0, 0);
            acc[mt][nt] = __builtin_amdgcn_mfma_f32_16x16x32_bf16(A4[mt][1], B4[nt][1], acc[mt][nt], 0, 0, 0);
        }
    #pragma unroll
    for (int mt = 0; mt < 4; ++mt)
        #pragma unroll
        for (int nt = 0; nt < 4; ++nt) {
            int pt = nt*16 + cc, hid = mt*16 + kb*4;
            *(uint2*)(Hs + pt*72 + hid) =
                make_uint2(packrelu2(acc[mt][nt][0], acc[mt][nt][1]),
                           packrelu2(acc[mt][nt][2], acc[mt][nt][3]));
        }

    // ===== GEMM5: rgb = sigmoid(WTh3[16x64] @ h2[64x64]), rows 0..2 =====
    bf16x8 A5[2];
    #pragma unroll
    for (int ks = 0; ks < 2; ++ks)
        A5[ks] = *(const bf16x8*)(WTh3 + cc*64 + ks*32 + kb*8);
    #pragma unroll
    for (int nt = 0; nt < 4; ++nt) {
        bf16x8 b0 = *(const bf16x8*)(Hs + (nt*16 + cc)*72 +  0 + kb*8);
        bf16x8 b1 = *(const bf16x8*)(Hs + (nt*16 + cc)*72 + 32 + kb*8);
        f32x4 a3 = __builtin_amdgcn_mfma_f32_16x16x32_bf16(A5[0], b0, zero4, 0, 0, 0);
        a3 = __builtin_amdgcn_mfma_f32_16x16x32_bf16(A5[1], b1, a3, 0, 0, 0);
        if (kb == 0) {
            size_t p = (size_t)(ptbase + nt*16 + cc);
            out[3*p + 0] = 1.f / (1.f + expf(-a3[0]));
            out[3*p + 1] = 1.f / (1.f + expf(-a3[1]));
            out[3*p + 2] = 1.f / (1.f + expf(-a3[2]));
        }
    }
}

// ---------------------------------------------------------------
// Fallback: proven fused scalar kernel (ws too small / odd n).
// ---------------------------------------------------------------
__global__ __launch_bounds__(256) void ngp_fused_kernel(
    const float* __restrict__ pos,
    const float* __restrict__ dirs,
    const float* __restrict__ aabb,
    const float* __restrict__ table,
    const float* __restrict__ wb1,
    const float* __restrict__ wb2,
    const float* __restrict__ wh1,
    const float* __restrict__ wh2,
    const float* __restrict__ wh3,
    float* __restrict__ out,
    int n, LevelParams lp)
{
    int i = blockIdx.x * blockDim.x + threadIdx.x;
    if (i >= n) return;

    float px = pos[3*i+0], py = pos[3*i+1], pz = pos[3*i+2];
    float mn0 = aabb[0], mn1 = aabb[1], mn2 = aabb[2];
    float mx0 = aabb[3], mx1 = aabb[4], mx2 = aabb[5];
    float x = (px - mn0) / (mx0 - mn0);
    float y = (py - mn1) / (mx1 - mn1);
    float z = (pz - mn2) / (mx2 - mn2);

    float enc[2*NLEV];
    #pragma unroll
    for (int l = 0; l < NLEV; ++l) {
        float s = lp.scale[l];
        unsigned res = lp.res[l];
        bool hashed = (lp.hashed_mask >> l) & 1u;
        float xs = fmaf(x, s, 0.5f);
        float ys = fmaf(y, s, 0.5f);
        float zs = fmaf(z, s, 0.5f);
        float fx = floorf(xs), fy = floorf(ys), fz = floorf(zs);
        float wx = xs - fx, wy = ys - fy, wz = zs - fz;
        unsigned ux = (unsigned)fx, uy = (unsigned)fy, uz = (unsigned)fz;
        const float2* tl = (const float2*)table + (size_t)l * TSZ;
        float a0 = 0.f, a1 = 0.f;
        #pragma unroll
        for (int c = 0; c < 8; ++c) {
            unsigned cx = ux + (c & 1);
            unsigned cy = uy + ((c >> 1) & 1);
            unsigned cz = uz + ((c >> 2) & 1);
            unsigned idx;
            if (hashed)
                idx = (cx ^ (cy * 2654435761u) ^ (cz * 805459861u)) & (TSZ - 1u);
            else
                idx = cx + cy * res + cz * res * res;
            float cw = ((c & 1) ? wx : 1.f - wx)
                     * (((c >> 1) & 1) ? wy : 1.f - wy)
                     * (((c >> 2) & 1) ? wz : 1.f - wz);
            float2 f = tl[idx];
            a0 = fmaf(f.x, cw, a0);
            a1 = fmaf(f.y, cw, a1);
        }
        enc[2*l]   = a0;
        enc[2*l+1] = a1;
    }

    float h[HID];
    #pragma unroll
    for (int j = 0; j < HID; ++j) h[j] = 0.f;
    #pragma unroll
    for (int k = 0; k < 2*NLEV; ++k) {
        float e = enc[k];
        #pragma unroll
        for (int j = 0; j < HID; ++j)
            h[j] = fmaf(e, wb1[k*HID+j], h[j]);
    }
    #pragma unroll
    for (int j = 0; j < HID; ++j) h[j] = fmaxf(h[j], 0.f);

    float bo[16];
    #pragma unroll
    for (int j = 0; j < 16; ++j) bo[j] = 0.f;
    #pragma unroll
    for (int k = 0; k < HID; ++k) {
        float e = h[k];
        #pragma unroll
        for (int j = 0; j < 16; ++j)
            bo[j] = fmaf(e, wb2[k*16+j], bo[j]);
    }
    float density = expf(bo[0] - 1.0f);

    float t0 = (dirs[3*i+0] + 1.f) * 0.5f;
    float t1 = (dirs[3*i+1] + 1.f) * 0.5f;
    float t2 = (dirs[3*i+2] + 1.f) * 0.5f;
    float dx = t0*2.f - 1.f, dy = t1*2.f - 1.f, dz = t2*2.f - 1.f;
    float x2 = dx*dx, y2 = dy*dy, z2 = dz*dz;
    float xy = dx*dy, xz = dx*dz, yz = dy*dz;
    float hh[31];
    hh[0]  = 0.28209479177387814f;
    hh[1]  = -0.48860251190291987f * dy;
    hh[2]  = 0.48860251190291987f * dz;
    hh[3]  = -0.48860251190291987f * dx;
    hh[4]  = 1.0925484305920792f * xy;
    hh[5]  = -1.0925484305920792f * yz;
    hh[6]  = 0.94617469575756f * z2 - 0.31539156525252f;
    hh[7]  = -1.0925484305920792f * xz;
    hh[8]  = 0.5462742152960396f * x2 - 0.5462742152960396f * y2;
    hh[9]  = 0.5900435899266435f * dy * (-3.f*x2 + y2);
    hh[10] = 2.890611442640554f * xy * dz;
    hh[11] = 0.4570457994644657f * dy * (1.f - 5.f*z2);
    hh[12] = 0.3731763325901154f * dz * (5.f*z2 - 3.f);
    hh[13] = 0.4570457994644657f * dx * (1.f - 5.f*z2);
    hh[14] = 1.445305721320277f * dz * (x2 - y2);
    hh[15] = 0.5900435899266435f * dx * (x2 - 3.f*y2);
    #pragma unroll
    for (int j = 0; j < 15; ++j) hh[16+j] = bo[1+j];

    float h1[HID];
    #pragma unroll
    for (int j = 0; j < HID; ++j) h1[j] = 0.f;
    #pragma unroll
    for (int k = 0; k < 31; ++k) {
        float e = hh[k];
        #pragma unroll
        for (int j = 0; j < HID; ++j)
            h1[j] = fmaf(e, wh1[k*HID+j], h1[j]);
    }
    #pragma unroll
    for (int j = 0; j < HID; ++j) h1[j] = fmaxf(h1[j], 0.f);

    float h2[HID];
    #pragma unroll
    for (int j = 0; j < HID; ++j) h2[j] = 0.f;
    #pragma unroll
    for (int k = 0; k < HID; ++k) {
        float e = h1[k];
        #pragma unroll
        for (int j = 0; j < HID; ++j)
            h2[j] = fmaf(e, wh2[k*HID+j], h2[j]);
    }
    #pragma unroll
    for (int j = 0; j < HID; ++j) h2[j] = fmaxf(h2[j], 0.f);

    float r0 = 0.f, r1 = 0.f, r2 = 0.f;
    #pragma unroll
    for (int k = 0; k < HID; ++k) {
        float e = h2[k];
        r0 = fmaf(e, wh3[k*3+0], r0);
        r1 = fmaf(e, wh3[k*3+1], r1);
        r2 = fmaf(e, wh3[k*3+2], r2);
    }
    r0 = 1.f / (1.f + expf(-r0));
    r1 = 1.f / (1.f + expf(-r1));
    r2 = 1.f / (1.f + expf(-r2));

    out[3*i+0] = r0;
    out[3*i+1] = r1;
    out[3*i+2] = r2;
    out[(size_t)3*n + i] = density;
}

extern "C" void kernel_launch(void* const* d_in, const int* in_sizes, int n_in,
                              void* d_out, int out_size, void* d_ws, size_t ws_size,
                              hipStream_t stream) {
    const float* pos   = (const float*)d_in[0];
    const float* dirs  = (const float*)d_in[1];
    const float* aabb  = (const float*)d_in[2];
    const float* table = (const float*)d_in[3];
    const float* wb1   = (const float*)d_in[4];
    const float* wb2   = (const float*)d_in[5];
    const float* wh1   = (const float*)d_in[6];
    const float* wh2   = (const float*)d_in[7];
    const float* wh3   = (const float*)d_in[8];
    float* out = (float*)d_out;
    int n = in_sizes[0] / 3;

    size_t need_basic = 32768 + (size_t)n * 64;                      // weights + enc
    size_t need_full  = need_basic + (size_t)NLEV * TSZ * 4;         // + bf16 table
    if (ws_size >= need_basic && (n & 511) == 0) {
        unsigned short* W = (unsigned short*)d_ws;
        unsigned* enc = (unsigned*)(W + OFF_ENC);
        int use_bf16 = (ws_size >= need_full) ? 1 : 0;
        unsigned* tbl_bf = (unsigned*)(W + OFF_ENC + (size_t)n * 32);

        ngp_prep_weights<<<40, 256, 0, stream>>>(wb1, wb2, wh1, wh2, wh3, W);
        if (use_bf16) {
            int conv_blocks = (int)((size_t)NLEV * TSZ / 256);
            ngp_conv_table<<<conv_blocks, 256, 0, stream>>>((const float2*)table, tbl_bf);
        }
        int bpl = n >> 9;
        ngp_encode_lm3_kernel<<<NLEV * bpl, 256, 0, stream>>>(
            pos, aabb, (const float2*)table, tbl_bf, use_bf16, enc, n);
        ngp_mlp_mfma_kernel<<<n / 256, 256, 0, stream>>>(W, dirs, out, n);
    } else {
        LevelParams lp;
        lp.hashed_mask = 0;
        double pls = exp((log(4096.0) - log(16.0)) / 15.0);
        for (int l = 0; l < NLEV; ++l) {
            double scale = 16.0 * pow(pls, (double)l) - 1.0;
            unsigned res = (unsigned)ceil(scale) + 1u;
            lp.scale[l] = (float)scale;
            lp.res[l] = res;
            if ((unsigned long long)res*(unsigned long long)res*(unsigned long long)res
                > (unsigned long long)TSZ)
                lp.hashed_mask |= (1u << l);
        }
        int block = 256;
        int grid = (n + block - 1) / block;
        ngp_fused_kernel<<<grid, block, 0, stream>>>(pos, dirs, aabb, table,
            wb1, wb2, wh1, wh2, wh3, out, n, lp);
    }
}

// Round 10
// 526.337 us; speedup vs baseline: 17.0247x; 1.0397x over previous
//
#include <hip/hip_runtime.h>
#include <math.h>

namespace {
constexpr int NLEV = 16;
constexpr unsigned TSZ = 1u << 19;
constexpr int HID = 64;

// ws layout (ushort elements):
//   [0,16384)            weights (see below)
//   [16384, 16384+n*32)  enc bf16, layout [16 levels][n] dwords
//   [16384+n*32, ...)    bf16-packed table [16][TSZ] dwords (optional)
constexpr int OFF_WT1  = 0;
constexpr int OFF_WT2  = 2048;
constexpr int OFF_WTH1 = 3072;
constexpr int OFF_WTH2 = 5120;
constexpr int OFF_WTH3 = 9216;
constexpr int OFF_ENC  = 16384;

struct LevelParams {
    float scale[NLEV];
    unsigned res[NLEV];
    unsigned hashed_mask;
};

typedef short bf16x8 __attribute__((ext_vector_type(8)));
typedef float f32x4 __attribute__((ext_vector_type(4)));
} // namespace

__device__ inline unsigned short f2bf(float f) {
    union { float f; unsigned u; } v; v.f = f;
    unsigned r = v.u + 0x7fffu + ((v.u >> 16) & 1u);
    return (unsigned short)(r >> 16);
}
__device__ inline float bf2f(unsigned hi16) {
    union { unsigned u; float f; } v; v.u = hi16 << 16;
    return v.f;
}
__device__ inline unsigned packrelu2(float a, float b) {
    a = fmaxf(a, 0.f); b = fmaxf(b, 0.f);
    return (unsigned)f2bf(a) | ((unsigned)f2bf(b) << 16);
}

// ---------------------------------------------------------------
// Weight prep: transpose + bf16-convert all MLP weights into ws.
// ---------------------------------------------------------------
__global__ void ngp_prep_weights(
    const float* __restrict__ wb1, const float* __restrict__ wb2,
    const float* __restrict__ wh1, const float* __restrict__ wh2,
    const float* __restrict__ wh3, unsigned short* __restrict__ W)
{
    int i = blockIdx.x * 256 + threadIdx.x;
    if (i >= 10240) return;
    float v; int o = i;
    if (o < 2048) {                      // WT1 [64][32]: wb1[k*64+m]
        int m = o >> 5, k = o & 31;
        v = wb1[k * 64 + m];
    } else if ((o -= 2048) < 1024) {     // WT2 [16][64]: wb2[k*16+m]
        int m = o >> 6, k = o & 63;
        v = wb2[k * 16 + m];
    } else if ((o -= 1024) < 2048) {     // WTh1 [64][32]: wh1[k*64+m], k<31
        int m = o >> 5, k = o & 31;
        v = (k < 31) ? wh1[k * 64 + m] : 0.f;
    } else if ((o -= 2048) < 4096) {     // WTh2 [64][64]: wh2[k*64+m]
        int m = o >> 6, k = o & 63;
        v = wh2[k * 64 + m];
    } else {                             // WTh3 [16][64]: wh3[k*3+m], m<3
        o -= 4096;
        int m = o >> 6, k = o & 63;
        v = (m < 3) ? wh3[k * 3 + m] : 0.f;
    }
    W[i] = f2bf(v);
}

// ---------------------------------------------------------------
// Table conversion: f32 float2 -> packed bf16x2, 4 entries/thread.
// ---------------------------------------------------------------
__global__ __launch_bounds__(256) void ngp_conv_table(
    const float4* __restrict__ table4, uint2* __restrict__ tbl_bf2)
{
    size_t i = (size_t)blockIdx.x * 256 + threadIdx.x;
    #pragma unroll
    for (int q = 0; q < 2; ++q) {
        float4 f = table4[2*i + q];
        tbl_bf2[2*i + q] = make_uint2(
            (unsigned)f2bf(f.x) | ((unsigned)f2bf(f.y) << 16),
            (unsigned)f2bf(f.z) | ((unsigned)f2bf(f.w) << 16));
    }
}

// ---------------------------------------------------------------
// Pass 1 v4: level-major encode, 2 points/thread, BATCHED loads.
// All 16 gathers issued before any consumption (latency hiding).
// Near the divergent-gather request-rate floor (R7-R9 evidence).
// enc layout: [level][point] dwords.
// ---------------------------------------------------------------
__global__ __launch_bounds__(256) void ngp_encode_lm3_kernel(
    const float* __restrict__ pos,
    const float* __restrict__ aabb,
    const float2* __restrict__ tbl_f32,
    const unsigned* __restrict__ tbl_bf,
    int use_bf16,
    unsigned* __restrict__ enc_u32,   // [16][n] dwords
    int n)
{
    int bpl = n >> 9;                  // blocks per level (512 pts/block)
    int l = blockIdx.x / bpl;
    int pb = (blockIdx.x - l * bpl) * 512 + threadIdx.x;

    float mn0 = aabb[0], mn1 = aabb[1], mn2 = aabb[2];
    float mx0 = aabb[3], mx1 = aabb[4], mx2 = aabb[5];

    // scale = 16 * (2^(8/15))^l - 1 = 2^(4 + 8l/15) - 1
    float s = exp2f(fmaf((float)l, 8.0f / 15.0f, 4.0f)) - 1.0f;
    unsigned res = (unsigned)ceilf(s) + 1u;
    bool hashed = (unsigned long long)res * res * res > (unsigned long long)TSZ;

    unsigned idx[2][8];
    float cw[2][8];

    // ---- phase A: addresses + weights for both points ----
    #pragma unroll
    for (int q = 0; q < 2; ++q) {
        int p = pb + q * 256;
        float x = (pos[3*p+0] - mn0) / (mx0 - mn0);
        float y = (pos[3*p+1] - mn1) / (mx1 - mn1);
        float z = (pos[3*p+2] - mn2) / (mx2 - mn2);

        float xs = fmaf(x, s, 0.5f);
        float ys = fmaf(y, s, 0.5f);
        float zs = fmaf(z, s, 0.5f);
        float fx = floorf(xs), fy = floorf(ys), fz = floorf(zs);
        float wx = xs - fx, wy = ys - fy, wz = zs - fz;
        unsigned ux = (unsigned)fx, uy = (unsigned)fy, uz = (unsigned)fz;
        float wx0 = 1.f - wx, wy0 = 1.f - wy, wz0 = 1.f - wz;

        #pragma unroll
        for (int j = 0; j < 4; ++j) {
            unsigned cy = uy + (j & 1);
            unsigned cz = uz + (j >> 1);
            unsigned i0, i1;
            if (hashed) {
                unsigned h = (cy * 2654435761u) ^ (cz * 805459861u);
                i0 = (ux ^ h) & (TSZ - 1u);
                i1 = ((ux + 1u) ^ h) & (TSZ - 1u);
            } else {
                i0 = ux + cy * res + cz * res * res;
                i1 = i0 + 1u;
            }
            idx[q][2*j]   = i0;
            idx[q][2*j+1] = i1;
            float cwyz = ((j & 1) ? wy : wy0) * ((j >> 1) ? wz : wz0);
            cw[q][2*j]   = wx0 * cwyz;
            cw[q][2*j+1] = wx  * cwyz;
        }
    }

    if (use_bf16) {
        const unsigned* tl = tbl_bf + (size_t)l * TSZ;
        unsigned u[2][8];
        // ---- phase B: issue ALL 16 gathers back-to-back ----
        #pragma unroll
        for (int q = 0; q < 2; ++q)
            #pragma unroll
            for (int c = 0; c < 8; ++c)
                u[q][c] = tl[idx[q][c]];
        // ---- phase C: consume ----
        #pragma unroll
        for (int q = 0; q < 2; ++q) {
            float a0 = 0.f, a1 = 0.f;
            #pragma unroll
            for (int c = 0; c < 8; ++c) {
                a0 = fmaf(bf2f(u[q][c] & 0xffffu), cw[q][c], a0);
                a1 = fmaf(bf2f(u[q][c] >> 16),     cw[q][c], a1);
            }
            enc_u32[(size_t)l * n + pb + q * 256] =
                (unsigned)f2bf(a0) | ((unsigned)f2bf(a1) << 16);
        }
    } else {
        const float2* tl = tbl_f32 + (size_t)l * TSZ;
        float2 u[2][8];
        #pragma unroll
        for (int q = 0; q < 2; ++q)
            #pragma unroll
            for (int c = 0; c < 8; ++c)
                u[q][c] = tl[idx[q][c]];
        #pragma unroll
        for (int q = 0; q < 2; ++q) {
            float a0 = 0.f, a1 = 0.f;
            #pragma unroll
            for (int c = 0; c < 8; ++c) {
                a0 = fmaf(u[q][c].x, cw[q][c], a0);
                a1 = fmaf(u[q][c].y, cw[q][c], a1);
            }
            enc_u32[(size_t)l * n + pb + q * 256] =
                (unsigned)f2bf(a0) | ((unsigned)f2bf(a1) << 16);
        }
    }
}

// ---------------------------------------------------------------
// Pass 2: MFMA MLPs. 4 waves/block, each wave owns 64 points.
// LDS: ONE buffer per wave (9216 B). HH (the 32-dim head input)
// ALIASES the h buffer: Hs holds h only between GEMM1-write and
// GEMM2-read; HH is written after GEMM2's reads and consumed by
// GEMM3's reads before GEMM3 writes h1 back into Hs. All accesses
// are wave-private and same-wave LDS ops execute in program order,
// so the alias is race-free. 36.9 KB/block -> 4 blocks/CU.
// Frag mapping (16x16x32 bf16, m89/m97-verified):
//   A: lane = m + 16*kb  holds A[m][kb*8+j]
//   B: lane = n + 16*kb  holds B[kb*8+j][n]
//   C: col = lane&15, row = (lane>>4)*4 + reg
// ---------------------------------------------------------------
__global__ __launch_bounds__(256) void ngp_mlp_mfma_kernel(
    const unsigned short* __restrict__ W,
    const float* __restrict__ dirs,
    float* __restrict__ out,
    int n)
{
    const unsigned short* WT1  = W + OFF_WT1;
    const unsigned short* WT2  = W + OFF_WT2;
    const unsigned short* WTh1 = W + OFF_WTH1;
    const unsigned short* WTh2 = W + OFF_WTH2;
    const unsigned short* WTh3 = W + OFF_WTH3;
    const unsigned* encb = (const unsigned*)(W + OFF_ENC);

    __shared__ unsigned short Hbuf[4][64 * 72];   // [pt][64+pad] bf16

    const int wv = threadIdx.x >> 6;
    const int lane = threadIdx.x & 63;
    const int cc = lane & 15;
    const int kb = lane >> 4;
    const int ptbase = (blockIdx.x * 4 + wv) * 64;

    unsigned short* Hs = Hbuf[wv];
    unsigned short* HH = Hbuf[wv];   // alias: see header comment

    const f32x4 zero4 = {0.f, 0.f, 0.f, 0.f};

    // ===== GEMM1: h = relu(WT1[64x32] @ enc[32x64]) =====
    bf16x8 Be[4], A1[4];
    #pragma unroll
    for (int nt = 0; nt < 4; ++nt) {
        union { unsigned u[4]; bf16x8 v; } uu;
        int p = ptbase + nt*16 + cc;
        #pragma unroll
        for (int q = 0; q < 4; ++q)
            uu.u[q] = encb[(size_t)(kb*4 + q) * n + p];
        Be[nt] = uu.v;
    }
    #pragma unroll
    for (int mt = 0; mt < 4; ++mt)
        A1[mt] = *(const bf16x8*)(WT1 + (mt*16 + cc)*32 + kb*8);
    f32x4 acc[4][4];
    #pragma unroll
    for (int mt = 0; mt < 4; ++mt)
        #pragma unroll
        for (int nt = 0; nt < 4; ++nt)
            acc[mt][nt] = __builtin_amdgcn_mfma_f32_16x16x32_bf16(A1[mt], Be[nt], zero4, 0, 0, 0);
    #pragma unroll
    for (int mt = 0; mt < 4; ++mt)
        #pragma unroll
        for (int nt = 0; nt < 4; ++nt) {
            int pt = nt*16 + cc, hid = mt*16 + kb*4;
            *(uint2*)(Hs + pt*72 + hid) =
                make_uint2(packrelu2(acc[mt][nt][0], acc[mt][nt][1]),
                           packrelu2(acc[mt][nt][2], acc[mt][nt][3]));
        }

    // ===== GEMM2: bo = WT2[16x64] @ h[64x64]  (no activation) =====
    bf16x8 A2[2];
    #pragma unroll
    for (int ks = 0; ks < 2; ++ks)
        A2[ks] = *(const bf16x8*)(WT2 + cc*64 + ks*32 + kb*8);
    f32x4 acc2[4];
    #pragma unroll
    for (int nt = 0; nt < 4; ++nt) {
        bf16x8 b0 = *(const bf16x8*)(Hs + (nt*16 + cc)*72 +  0 + kb*8);
        bf16x8 b1 = *(const bf16x8*)(Hs + (nt*16 + cc)*72 + 32 + kb*8);
        acc2[nt] = __builtin_amdgcn_mfma_f32_16x16x32_bf16(A2[0], b0, zero4, 0, 0, 0);
        acc2[nt] = __builtin_amdgcn_mfma_f32_16x16x32_bf16(A2[1], b1, acc2[nt], 0, 0, 0);
    }

    // ===== SH encode (lane <-> point) into HH[pt][0..15] =====
    // (overwrites dead h storage; GEMM2 reads completed above)
    {
        int p = ptbase + lane;
        float t0 = (dirs[3*p+0] + 1.f) * 0.5f;
        float t1 = (dirs[3*p+1] + 1.f) * 0.5f;
        float t2 = (dirs[3*p+2] + 1.f) * 0.5f;
        float dx = t0*2.f - 1.f, dy = t1*2.f - 1.f, dz = t2*2.f - 1.f;
        float x2 = dx*dx, y2 = dy*dy, z2 = dz*dz;
        float xy = dx*dy, xz = dx*dz, yz = dy*dz;
        float sh[16];
        sh[0]  = 0.28209479177387814f;
        sh[1]  = -0.48860251190291987f * dy;
        sh[2]  = 0.48860251190291987f * dz;
        sh[3]  = -0.48860251190291987f * dx;
        sh[4]  = 1.0925484305920792f * xy;
        sh[5]  = -1.0925484305920792f * yz;
        sh[6]  = 0.94617469575756f * z2 - 0.31539156525252f;
        sh[7]  = -1.0925484305920792f * xz;
        sh[8]  = 0.5462742152960396f * x2 - 0.5462742152960396f * y2;
        sh[9]  = 0.5900435899266435f * dy * (-3.f*x2 + y2);
        sh[10] = 2.890611442640554f * xy * dz;
        sh[11] = 0.4570457994644657f * dy * (1.f - 5.f*z2);
        sh[12] = 0.3731763325901154f * dz * (5.f*z2 - 3.f);
        sh[13] = 0.4570457994644657f * dx * (1.f - 5.f*z2);
        sh[14] = 1.445305721320277f * dz * (x2 - y2);
        sh[15] = 0.5900435899266435f * dx * (x2 - 3.f*y2);
        unsigned u[8];
        #pragma unroll
        for (int j = 0; j < 8; ++j)
            u[j] = (unsigned)f2bf(sh[2*j]) | ((unsigned)f2bf(sh[2*j+1]) << 16);
        *(uint4*)(HH + lane*40)     = make_uint4(u[0], u[1], u[2], u[3]);
        *(uint4*)(HH + lane*40 + 8) = make_uint4(u[4], u[5], u[6], u[7]);
    }

    // geo -> HH[pt][16..30]; row 0 (density) parked in dead slot 31
    // (WTh1 row k=31 is zeroed, so hh[31] never contributes).
    #pragma unroll
    for (int nt = 0; nt < 4; ++nt) {
        int pt = nt*16 + cc;
        #pragma unroll
        for (int r = 0; r < 4; ++r) {
            int row = kb*4 + r;
            int slot = (row == 0) ? 31 : (15 + row);
            HH[pt*40 + slot] = f2bf(acc2[nt][r]);
        }
        if (kb == 0)
            out[(size_t)3*n + ptbase + pt] = expf(acc2[nt][0] - 1.0f);
    }

    // ===== GEMM3: h1 = relu(WTh1[64x32] @ hh[32x64]) =====
    // Bh reads precede the h1 writes below (same-wave in-order LDS).
    bf16x8 A3[4], Bh[4];
    #pragma unroll
    for (int mt = 0; mt < 4; ++mt)
        A3[mt] = *(const bf16x8*)(WTh1 + (mt*16 + cc)*32 + kb*8);
    #pragma unroll
    for (int nt = 0; nt < 4; ++nt)
        Bh[nt] = *(const bf16x8*)(HH + (nt*16 + cc)*40 + kb*8);
    #pragma unroll
    for (int mt = 0; mt < 4; ++mt)
        #pragma unroll
        for (int nt = 0; nt < 4; ++nt)
            acc[mt][nt] = __builtin_amdgcn_mfma_f32_16x16x32_bf16(A3[mt], Bh[nt], zero4, 0, 0, 0);
    #pragma unroll
    for (int mt = 0; mt < 4; ++mt)
        #pragma unroll
        for (int nt = 0; nt < 4; ++nt) {
            int pt = nt*16 + cc, hid = mt*16 + kb*4;
            *(uint2*)(Hs + pt*72 + hid) =
                make_uint2(packrelu2(acc[mt][nt][0], acc[mt][nt][1]),
                           packrelu2(acc[mt][nt][2], acc[mt][nt][3]));
        }

    // ===== GEMM4: h2 = relu(WTh2[64x64] @ h1[64x64]) =====
    bf16x8 A4[4][2], B4[4][2];
    #pragma unroll
    for (int mt = 0; mt < 4; ++mt)
        #pragma unroll
        for (int ks = 0; ks < 2; ++ks)
            A4[mt][ks] = *(const bf16x8*)(WTh2 + (mt*16 + cc)*64 + ks*32 + kb*8);
    #pragma unroll
    for (int nt = 0; nt < 4; ++nt)
        #pragma unroll
        for (int ks = 0; ks < 2; ++ks)
            B4[nt][ks] = *(const bf16x8*)(Hs + (nt*16 + cc)*72 + ks*32 + kb*8);
    #pragma unroll
    for (int mt = 0; mt < 4; ++mt)
        #pragma unroll
        for (int nt = 0; nt < 4; ++nt) {
            acc[mt][nt] = __builtin_amdgcn_mfma_f32_16x16x32_bf16(A4[mt][0], B4[nt][0], zero4, 0, 0, 0);
            acc[mt][nt] = __builtin_amdgcn_mfma_f32_16x16x32_bf16(A4[mt][1], B4[nt][1], acc[mt][nt], 0, 0, 0);
        }
    #pragma unroll
    for (int mt = 0; mt < 4; ++mt)
        #pragma unroll
        for (int nt = 0; nt < 4; ++nt) {
            int pt = nt*16 + cc, hid = mt*16 + kb*4;
            *(uint2*)(Hs + pt*72 + hid) =
                make_uint2(packrelu2(acc[mt][nt][0], acc[mt][nt][1]),
                           packrelu2(acc[mt][nt][2], acc[mt][nt][3]));
        }

    // ===== GEMM5: rgb = sigmoid(WTh3[16x64] @ h2[64x64]), rows 0..2 =====
    bf16x8 A5[2];
    #pragma unroll
    for (int ks = 0; ks < 2; ++ks)
        A5[ks] = *(const bf16x8*)(WTh3 + cc*64 + ks*32 + kb*8);
    #pragma unroll
    for (int nt = 0; nt < 4; ++nt) {
        bf16x8 b0 = *(const bf16x8*)(Hs + (nt*16 + cc)*72 +  0 + kb*8);
        bf16x8 b1 = *(const bf16x8*)(Hs + (nt*16 + cc)*72 + 32 + kb*8);
        f32x4 a3 = __builtin_amdgcn_mfma_f32_16x16x32_bf16(A5[0], b0, zero4, 0, 0, 0);
        a3 = __builtin_amdgcn_mfma_f32_16x16x32_bf16(A5[1], b1, a3, 0, 0, 0);
        if (kb == 0) {
            size_t p = (size_t)(ptbase + nt*16 + cc);
            out[3*p + 0] = 1.f / (1.f + expf(-a3[0]));
            out[3*p + 1] = 1.f / (1.f + expf(-a3[1]));
            out[3*p + 2] = 1.f / (1.f + expf(-a3[2]));
        }
    }
}

// ---------------------------------------------------------------
// Fallback: proven fused scalar kernel (ws too small / odd n).
// ---------------------------------------------------------------
__global__ __launch_bounds__(256) void ngp_fused_kernel(
    const float* __restrict__ pos,
    const float* __restrict__ dirs,
    const float* __restrict__ aabb,
    const float* __restrict__ table,
    const float* __restrict__ wb1,
    const float* __restrict__ wb2,
    const float* __restrict__ wh1,
    const float* __restrict__ wh2,
    const float* __restrict__ wh3,
    float* __restrict__ out,
    int n, LevelParams lp)
{
    int i = blockIdx.x * blockDim.x + threadIdx.x;
    if (i >= n) return;

    float px = pos[3*i+0], py = pos[3*i+1], pz = pos[3*i+2];
    float mn0 = aabb[0], mn1 = aabb[1], mn2 = aabb[2];
    float mx0 = aabb[3], mx1 = aabb[4], mx2 = aabb[5];
    float x = (px - mn0) / (mx0 - mn0);
    float y = (py - mn1) / (mx1 - mn1);
    float z = (pz - mn2) / (mx2 - mn2);

    float enc[2*NLEV];
    #pragma unroll
    for (int l = 0; l < NLEV; ++l) {
        float s = lp.scale[l];
        unsigned res = lp.res[l];
        bool hashed = (lp.hashed_mask >> l) & 1u;
        float xs = fmaf(x, s, 0.5f);
        float ys = fmaf(y, s, 0.5f);
        float zs = fmaf(z, s, 0.5f);
        float fx = floorf(xs), fy = floorf(ys), fz = floorf(zs);
        float wx = xs - fx, wy = ys - fy, wz = zs - fz;
        unsigned ux = (unsigned)fx, uy = (unsigned)fy, uz = (unsigned)fz;
        const float2* tl = (const float2*)table + (size_t)l * TSZ;
        float a0 = 0.f, a1 = 0.f;
        #pragma unroll
        for (int c = 0; c < 8; ++c) {
            unsigned cx = ux + (c & 1);
            unsigned cy = uy + ((c >> 1) & 1);
            unsigned cz = uz + ((c >> 2) & 1);
            unsigned idx;
            if (hashed)
                idx = (cx ^ (cy * 2654435761u) ^ (cz * 805459861u)) & (TSZ - 1u);
            else
                idx = cx + cy * res + cz * res * res;
            float cw = ((c & 1) ? wx : 1.f - wx)
                     * (((c >> 1) & 1) ? wy : 1.f - wy)
                     * (((c >> 2) & 1) ? wz : 1.f - wz);
            float2 f = tl[idx];
            a0 = fmaf(f.x, cw, a0);
            a1 = fmaf(f.y, cw, a1);
        }
        enc[2*l]   = a0;
        enc[2*l+1] = a1;
    }

    float h[HID];
    #pragma unroll
    for (int j = 0; j < HID; ++j) h[j] = 0.f;
    #pragma unroll
    for (int k = 0; k < 2*NLEV; ++k) {
        float e = enc[k];
        #pragma unroll
        for (int j = 0; j < HID; ++j)
            h[j] = fmaf(e, wb1[k*HID+j], h[j]);
    }
    #pragma unroll
    for (int j = 0; j < HID; ++j) h[j] = fmaxf(h[j], 0.f);

    float bo[16];
    #pragma unroll
    for (int j = 0; j < 16; ++j) bo[j] = 0.f;
    #pragma unroll
    for (int k = 0; k < HID; ++k) {
        float e = h[k];
        #pragma unroll
        for (int j = 0; j < 16; ++j)
            bo[j] = fmaf(e, wb2[k*16+j], bo[j]);
    }
    float density = expf(bo[0] - 1.0f);

    float t0 = (dirs[3*i+0] + 1.f) * 0.5f;
    float t1 = (dirs[3*i+1] + 1.f) * 0.5f;
    float t2 = (dirs[3*i+2] + 1.f) * 0.5f;
    float dx = t0*2.f - 1.f, dy = t1*2.f - 1.f, dz = t2*2.f - 1.f;
    float x2 = dx*dx, y2 = dy*dy, z2 = dz*dz;
    float xy = dx*dy, xz = dx*dz, yz = dy*dz;
    float hh[31];
    hh[0]  = 0.28209479177387814f;
    hh[1]  = -0.48860251190291987f * dy;
    hh[2]  = 0.48860251190291987f * dz;
    hh[3]  = -0.48860251190291987f * dx;
    hh[4]  = 1.0925484305920792f * xy;
    hh[5]  = -1.0925484305920792f * yz;
    hh[6]  = 0.94617469575756f * z2 - 0.31539156525252f;
    hh[7]  = -1.0925484305920792f * xz;
    hh[8]  = 0.5462742152960396f * x2 - 0.5462742152960396f * y2;
    hh[9]  = 0.5900435899266435f * dy * (-3.f*x2 + y2);
    hh[10] = 2.890611442640554f * xy * dz;
    hh[11] = 0.4570457994644657f * dy * (1.f - 5.f*z2);
    hh[12] = 0.3731763325901154f * dz * (5.f*z2 - 3.f);
    hh[13] = 0.4570457994644657f * dx * (1.f - 5.f*z2);
    hh[14] = 1.445305721320277f * dz * (x2 - y2);
    hh[15] = 0.5900435899266435f * dx * (x2 - 3.f*y2);
    #pragma unroll
    for (int j = 0; j < 15; ++j) hh[16+j] = bo[1+j];

    float h1[HID];
    #pragma unroll
    for (int j = 0; j < HID; ++j) h1[j] = 0.f;
    #pragma unroll
    for (int k = 0; k < 31; ++k) {
        float e = hh[k];
        #pragma unroll
        for (int j = 0; j < HID; ++j)
            h1[j] = fmaf(e, wh1[k*HID+j], h1[j]);
    }
    #pragma unroll
    for (int j = 0; j < HID; ++j) h1[j] = fmaxf(h1[j], 0.f);

    float h2[HID];
    #pragma unroll
    for (int j = 0; j < HID; ++j) h2[j] = 0.f;
    #pragma unroll
    for (int k = 0; k < HID; ++k) {
        float e = h1[k];
        #pragma unroll
        for (int j = 0; j < HID; ++j)
            h2[j] = fmaf(e, wh2[k*HID+j], h2[j]);
    }
    #pragma unroll
    for (int j = 0; j < HID; ++j) h2[j] = fmaxf(h2[j], 0.f);

    float r0 = 0.f, r1 = 0.f, r2 = 0.f;
    #pragma unroll
    for (int k = 0; k < HID; ++k) {
        float e = h2[k];
        r0 = fmaf(e, wh3[k*3+0], r0);
        r1 = fmaf(e, wh3[k*3+1], r1);
        r2 = fmaf(e, wh3[k*3+2], r2);
    }
    r0 = 1.f / (1.f + expf(-r0));
    r1 = 1.f / (1.f + expf(-r1));
    r2 = 1.f / (1.f + expf(-r2));

    out[3*i+0] = r0;
    out[3*i+1] = r1;
    out[3*i+2] = r2;
    out[(size_t)3*n + i] = density;
}

extern "C" void kernel_launch(void* const* d_in, const int* in_sizes, int n_in,
                              void* d_out, int out_size, void* d_ws, size_t ws_size,
                              hipStream_t stream) {
    const float* pos   = (const float*)d_in[0];
    const float* dirs  = (const float*)d_in[1];
    const float* aabb  = (const float*)d_in[2];
    const float* table = (const float*)d_in[3];
    const float* wb1   = (const float*)d_in[4];
    const float* wb2   = (const float*)d_in[5];
    const float* wh1   = (const float*)d_in[6];
    const float* wh2   = (const float*)d_in[7];
    const float* wh3   = (const float*)d_in[8];
    float* out = (float*)d_out;
    int n = in_sizes[0] / 3;

    size_t need_basic = 32768 + (size_t)n * 64;                      // weights + enc
    size_t need_full  = need_basic + (size_t)NLEV * TSZ * 4;         // + bf16 table
    if (ws_size >= need_basic && (n & 511) == 0) {
        unsigned short* W = (unsigned short*)d_ws;
        unsigned* enc = (unsigned*)(W + OFF_ENC);
        int use_bf16 = (ws_size >= need_full) ? 1 : 0;
        unsigned* tbl_bf = (unsigned*)(W + OFF_ENC + (size_t)n * 32);

        ngp_prep_weights<<<40, 256, 0, stream>>>(wb1, wb2, wh1, wh2, wh3, W);
        if (use_bf16) {
            int conv_blocks = (int)((size_t)NLEV * TSZ / 1024);
            ngp_conv_table<<<conv_blocks, 256, 0, stream>>>(
                (const float4*)table, (uint2*)tbl_bf);
        }
        int bpl = n >> 9;
        ngp_encode_lm3_kernel<<<NLEV * bpl, 256, 0, stream>>>(
            pos, aabb, (const float2*)table, tbl_bf, use_bf16, enc, n);
        ngp_mlp_mfma_kernel<<<n / 256, 256, 0, stream>>>(W, dirs, out, n);
    } else {
        LevelParams lp;
        lp.hashed_mask = 0;
        double pls = exp((log(4096.0) - log(16.0)) / 15.0);
        for (int l = 0; l < NLEV; ++l) {
            double scale = 16.0 * pow(pls, (double)l) - 1.0;
            unsigned res = (unsigned)ceil(scale) + 1u;
            lp.scale[l] = (float)scale;
            lp.res[l] = res;
            if ((unsigned long long)res*(unsigned long long)res*(unsigned long long)res
                > (unsigned long long)TSZ)
                lp.hashed_mask |= (1u << l);
        }
        int block = 256;
        int grid = (n + block - 1) / block;
        ngp_fused_kernel<<<grid, block, 0, stream>>>(pos, dirs, aabb, table,
            wb1, wb2, wh1, wh2, wh3, out, n, lp);
    }
}